// Round 5
// baseline (6517.319 us; speedup 1.0000x reference)
//
#include <hip/hip_runtime.h>

#define V_ 32000
#define D_ 512
#define R_ 512
#define E_ 512
#define B_ 32
#define T_ 64
#define S_ 64
#define BT_ (B_ * T_)   // 2048
#define G3_ (3 * R_)    // 1536
#define NWG 64          // persistent-kernel workgroups

typedef _Float16 f16;
typedef _Float16 f16x2 __attribute__((ext_vector_type(2)));
typedef _Float16 f16x4 __attribute__((ext_vector_type(4)));
typedef _Float16 f16x8 __attribute__((ext_vector_type(8)));
typedef __bf16 bf16x8 __attribute__((ext_vector_type(8)));
typedef float f32x4 __attribute__((ext_vector_type(4)));

#define PAIR(v, i) (f16x2){(v)[2*(i)], (v)[2*(i)+1]}

__device__ __forceinline__ float fdot2_(f16x2 a, f16x2 b, float c) {
    return __builtin_amdgcn_fdot2(a, b, c, false);
}
__device__ __forceinline__ float sigmoidf_(float x) {
    return 1.0f / (1.0f + __expf(-x));
}

// ---------------- fp32 -> bf16 convert ----------------
__global__ __launch_bounds__(256) void k_convert_bf16(const float* __restrict__ src,
                                                      __bf16* __restrict__ dst, int n8) {
    int i = blockIdx.x * 256 + threadIdx.x;
    if (i >= n8) return;
    float4 a = *(const float4*)&src[(size_t)i * 8];
    float4 b = *(const float4*)&src[(size_t)i * 8 + 4];
    bf16x8 o;
    o[0] = (__bf16)a.x; o[1] = (__bf16)a.y; o[2] = (__bf16)a.z; o[3] = (__bf16)a.w;
    o[4] = (__bf16)b.x; o[5] = (__bf16)b.y; o[6] = (__bf16)b.z; o[7] = (__bf16)b.w;
    *(bf16x8*)&dst[(size_t)i * 8] = o;
}

// ---------------- gather embedding rows (bf16) ----------------
__global__ __launch_bounds__(256) void k_gather_emb(const int* __restrict__ trg,
                                                    const __bf16* __restrict__ embW,
                                                    __bf16* __restrict__ dst) {
    int id = blockIdx.x * 256 + threadIdx.x;
    int bt = id >> 6, c = id & 63;
    int tok = trg[bt];
    *(uint4*)&dst[(size_t)bt * 512 + c * 8] = *(const uint4*)&embW[(size_t)tok * 512 + c * 8];
}

// ---------------- bf16 MFMA GEMM: C = A[M,K] * B^T[N,K] (+bias) ----------------
// 128x128 tile, BK=32, LDS rows padded 32->40 bf16 (bank-conflict fix).
__global__ __launch_bounds__(256) void k_gemm_bf16(const __bf16* __restrict__ A,
                                                   const __bf16* __restrict__ B,
                                                   const float* __restrict__ bias,
                                                   float* __restrict__ out,
                                                   int M, int N, int K, int lda, int ldb,
                                                   int mode) {
    __shared__ __bf16 lA[128 * 40];
    __shared__ __bf16 lB[128 * 40];
    const int Mt = M >> 7;
    const int mt = blockIdx.x % Mt, nt = blockIdx.x / Mt;
    const int m0 = mt << 7, n0 = nt << 7;
    const int tid = threadIdx.x;
    const int w = tid >> 6, ln = tid & 63;
    const int wm = w >> 1, wn = w & 1;

    f32x4 acc[4][4];
#pragma unroll
    for (int mi = 0; mi < 4; ++mi)
#pragma unroll
        for (int ni = 0; ni < 4; ++ni) acc[mi][ni] = (f32x4){0.f, 0.f, 0.f, 0.f};

    const int k0 = (ln >> 4) * 8, rr = ln & 15;

    for (int kk = 0; kk < K; kk += 32) {
        __syncthreads();
#pragma unroll
        for (int p = 0; p < 2; ++p) {
            int i = p * 256 + tid;
            int r = i >> 2, q = i & 3;
            *(uint4*)&lA[r * 40 + q * 8] = *(const uint4*)&A[(size_t)(m0 + r) * lda + kk + q * 8];
            *(uint4*)&lB[r * 40 + q * 8] = *(const uint4*)&B[(size_t)(n0 + r) * ldb + kk + q * 8];
        }
        __syncthreads();
        bf16x8 af[4], bf[4];
#pragma unroll
        for (int mi = 0; mi < 4; ++mi) af[mi] = *(bf16x8*)&lA[(wm * 64 + mi * 16 + rr) * 40 + k0];
#pragma unroll
        for (int ni = 0; ni < 4; ++ni) bf[ni] = *(bf16x8*)&lB[(wn * 64 + ni * 16 + rr) * 40 + k0];
#pragma unroll
        for (int mi = 0; mi < 4; ++mi)
#pragma unroll
            for (int ni = 0; ni < 4; ++ni)
                acc[mi][ni] = __builtin_amdgcn_mfma_f32_16x16x32_bf16(af[mi], bf[ni], acc[mi][ni], 0, 0, 0);
    }

    const int rq = ln >> 4;
#pragma unroll
    for (int mi = 0; mi < 4; ++mi) {
#pragma unroll
        for (int ni = 0; ni < 4; ++ni) {
            int col = n0 + wn * 64 + ni * 16 + rr;
            float bv = bias ? bias[col] : 0.f;
#pragma unroll
            for (int reg = 0; reg < 4; ++reg) {
                int row = m0 + wm * 64 + mi * 16 + rq * 4 + reg;
                float v = acc[mi][ni][reg] + bv;
                if (mode == 0) {
                    out[(size_t)row * N + col] = v;
                } else {
                    int bb = row >> 6, tt = row & 63;
                    out[((size_t)tt * G3_ + col) * B_ + bb] = v;
                }
            }
        }
    }
}

// ---------------- weight packing kernels (one-time) ----------------
// Wg[j3][k] f16, k<512: Wih[j3][512+k] (o-part), k>=512: Whh[j3][k-512]
__global__ __launch_bounds__(256) void k_pack_gates(const float* __restrict__ Wih,
                                                    const float* __restrict__ Whh,
                                                    f16* __restrict__ Wg) {
    int idx = blockIdx.x * 256 + threadIdx.x;  // 1536*1024
    int j3 = idx >> 10, k = idx & 1023;
    float v = (k < 512) ? Wih[(size_t)j3 * 1024 + 512 + k] : Whh[(size_t)j3 * 512 + (k - 512)];
    Wg[idx] = (f16)v;
}
// WhT[j][d] = Wh[d][j]
__global__ __launch_bounds__(256) void k_pack_whT(const float* __restrict__ Wh, f16* __restrict__ WhT) {
    int idx = blockIdx.x * 256 + threadIdx.x;  // 512*512
    int j = idx >> 9, d = idx & 511;
    WhT[idx] = (f16)Wh[(size_t)d * 512 + j];
}
// encprojT[j][b][s] = encproj[(b*64+s)][j]
__global__ __launch_bounds__(256) void k_pack_epT(const float* __restrict__ ep, f16* __restrict__ epT) {
    int idx = blockIdx.x * 256 + threadIdx.x;  // 512*32*64
    int j = idx >> 11, b = (idx >> 6) & 31, s = idx & 63;
    epT[idx] = (f16)ep[((size_t)b * 64 + s) * 512 + j];
}
// encWcT[b][d][s] = encWc[(b*64+s)][d]
__global__ __launch_bounds__(256) void k_pack_ewT(const float* __restrict__ ew, f16* __restrict__ ewT) {
    int idx = blockIdx.x * 256 + threadIdx.x;  // 32*512*64
    int b = idx >> 15, d = (idx >> 6) & 511, s = idx & 63;
    ewT[idx] = (f16)ew[((size_t)b * 64 + s) * 512 + d];
}
// x2[0] = [o=0 || h=init_h] f16; hbuf[0] = init_h f32
__global__ __launch_bounds__(256) void k_init_state(const float* __restrict__ init_h,
                                                    f16* __restrict__ x2, float* __restrict__ hbuf) {
    int idx = blockIdx.x * 256 + threadIdx.x;  // 32*1024
    int b = idx >> 10, k = idx & 1023;
    if (k < 512) {
        x2[idx] = (f16)0.f;
    } else {
        float v = init_h[(size_t)b * 512 + (k - 512)];
        x2[idx] = (f16)v;
        hbuf[(size_t)b * 512 + (k - 512)] = v;
    }
}

// ---------------- device-scope grid barrier ----------------
__device__ __forceinline__ void gridbar(int* bar) {
    __syncthreads();
    if (threadIdx.x == 0) {
        __threadfence();
        int g = __hip_atomic_load(bar + 1, __ATOMIC_RELAXED, __HIP_MEMORY_SCOPE_AGENT);
        int a = __hip_atomic_fetch_add(bar, 1, __ATOMIC_ACQ_REL, __HIP_MEMORY_SCOPE_AGENT);
        if (a == NWG - 1) {
            __hip_atomic_store(bar, 0, __ATOMIC_RELAXED, __HIP_MEMORY_SCOPE_AGENT);
            __hip_atomic_store(bar + 1, g + 1, __ATOMIC_RELEASE, __HIP_MEMORY_SCOPE_AGENT);
        } else {
            while (__hip_atomic_load(bar + 1, __ATOMIC_ACQUIRE, __HIP_MEMORY_SCOPE_AGENT) == g) {
                __builtin_amdgcn_s_sleep(2);
            }
        }
    }
    __syncthreads();
}

// ---------------- persistent recurrence kernel ----------------
// 64 wgs x 512 thr. Phase A: wg owns 8 j; thread=(b,half,jl). Phase B: wg=b (first 32).
__global__ __launch_bounds__(512, 2) void k_recur(
    const f16* __restrict__ Wg, const f16* __restrict__ WhT,
    const float* __restrict__ gxe, const float* __restrict__ bhh,
    const f16* __restrict__ encprojT, const f16* __restrict__ encWcT,
    const float* __restrict__ mask, const float* __restrict__ bh, const float* __restrict__ bc,
    f16* __restrict__ x2, float* __restrict__ hbuf,
    float* __restrict__ Up, float* __restrict__ SCp,
    __bf16* __restrict__ obf, int* __restrict__ bar) {
    __shared__ __align__(16) f16 x2l[32 * 1032];
    __shared__ float hnl[32 * 8];
    __shared__ float s_af[64];
    __shared__ f16x2 a2l[32];

    const int tid = threadIdx.x;
    const int wgid = blockIdx.x;
    // phase A mapping
    const int bA = tid & 31;
    const int half = (tid >> 5) & 1;
    const int jl = tid >> 6;          // 0..7
    const int j = wgid * 8 + jl;      // 0..511
    // phase A2/AS mapping
    const int dg = tid & 15, b2 = tid >> 4;

    for (int t = 0; t < T_; ++t) {
        const int cur = t & 1, nxt = cur ^ 1;
        const f16* x2c = x2 + (size_t)cur * 32 * 1024;
        f16* x2n = x2 + (size_t)nxt * 32 * 1024;
        const float* hsrc = hbuf + (size_t)cur * 32 * 512;
        float* hdst = hbuf + (size_t)nxt * 32 * 512;
        const float* gp = gxe + (size_t)t * G3_ * B_;

        // ---- stage x2[cur] into LDS (32 rows x 1024 f16, rows padded to 1032) ----
#pragma unroll
        for (int i = 0; i < 8; ++i) {
            int f = tid + i * 512;           // uint4 index, 4096 total = 32*128
            int row = f >> 7, col = f & 127;
            *(uint4*)(x2l + row * 1032 + col * 8) = *(const uint4*)(x2c + row * 1024 + col * 8);
        }
        __syncthreads();

        // ---- A1: gates + h_new ----
        {
            const f16* xb = x2l + bA * 1032 + half * 512;
            const f16* wr = Wg + (size_t)(j) * 1024 + half * 512;
            const f16* wz = Wg + (size_t)(512 + j) * 1024 + half * 512;
            const f16* wn = Wg + (size_t)(1024 + j) * 1024 + half * 512;
            float ar = 0.f, az = 0.f, an = 0.f;
#pragma unroll 4
            for (int c = 0; c < 64; ++c) {
                f16x8 xv = *(const f16x8*)(xb + c * 8);
                f16x8 wrv = *(const f16x8*)(wr + c * 8);
                f16x8 wzv = *(const f16x8*)(wz + c * 8);
                f16x8 wnv = *(const f16x8*)(wn + c * 8);
#pragma unroll
                for (int q = 0; q < 4; ++q) {
                    f16x2 xp = PAIR(xv, q);
                    ar = fdot2_(xp, PAIR(wrv, q), ar);
                    az = fdot2_(xp, PAIR(wzv, q), az);
                    an = fdot2_(xp, PAIR(wnv, q), an);
                }
            }
            float aro = __shfl_xor(ar, 32);
            float azo = __shfl_xor(az, 32);
            float ano = __shfl_xor(an, 32);
            float gr = gp[(size_t)j * 32 + bA];
            float gz = gp[(size_t)(512 + j) * 32 + bA];
            float gn = gp[(size_t)(1024 + j) * 32 + bA];
            float rpre = gr + bhh[j] + ar + aro;
            float zpre = gz + bhh[512 + j] + az + azo;
            float r = sigmoidf_(rpre);
            float z = sigmoidf_(zpre);
            float gxn = gn + (half ? ano : an);
            float ghn = bhh[1024 + j] + (half ? an : ano);
            float n = tanhf(gxn + r * ghn);
            float hp = hsrc[(size_t)bA * 512 + j];
            float hnew = (1.f - z) * n + z * hp;
            if (half == 0) {
                hdst[(size_t)bA * 512 + j] = hnew;
                x2n[(size_t)bA * 1024 + 512 + j] = (f16)hnew;
                hnl[bA * 8 + jl] = hnew;
            }
        }
        __syncthreads();

        // ---- A2: partial Wh*h_new over this wg's 8 j -> Up[wg][b][512] ----
        {
            float acc[32];
#pragma unroll
            for (int i = 0; i < 32; ++i) acc[i] = 0.f;
#pragma unroll
            for (int jj = 0; jj < 8; ++jj) {
                float hn = hnl[b2 * 8 + jj];
                const f16* wp = WhT + (size_t)(wgid * 8 + jj) * 512 + dg * 32;
#pragma unroll
                for (int c = 0; c < 4; ++c) {
                    f16x8 wv = *(const f16x8*)(wp + c * 8);
#pragma unroll
                    for (int e = 0; e < 8; ++e) acc[c * 8 + e] += (float)wv[e] * hn;
                }
            }
            float* up = Up + ((size_t)wgid * 32 + b2) * 512 + dg * 32;
#pragma unroll
            for (int c = 0; c < 8; ++c) {
                float4 v = {acc[c * 4], acc[c * 4 + 1], acc[c * 4 + 2], acc[c * 4 + 3]};
                *(float4*)(up + c * 4) = v;
            }
        }
        // ---- AS: partial scores over this wg's 8 j -> SCp[wg][b][64] ----
        {
            float a4[4] = {0.f, 0.f, 0.f, 0.f};
#pragma unroll
            for (int jj = 0; jj < 8; ++jj) {
                float hn = hnl[b2 * 8 + jj];
                const f16* ep = encprojT + ((size_t)(wgid * 8 + jj) * 32 + b2) * 64 + dg * 4;
                f16x4 ev = *(const f16x4*)ep;
#pragma unroll
                for (int e = 0; e < 4; ++e) a4[e] += (float)ev[e] * hn;
            }
            float4 v = {a4[0], a4[1], a4[2], a4[3]};
            *(float4*)(SCp + ((size_t)wgid * 32 + b2) * 64 + dg * 4) = v;
        }

        gridbar(bar);

        // ---- Phase B: per-b softmax + output (wgs 0..31) ----
        if (wgid < 32) {
            const int b = wgid;
            // u2 = sum of Wh*h partials (thread = d)
            float u2 = 0.f;
            {
                const float* up = Up + (size_t)b * 512 + tid;
#pragma unroll 8
                for (int p = 0; p < NWG; ++p) u2 += up[(size_t)p * 32 * 512];
            }
            // scores + softmax (wave 0)
            if (tid < 64) {
                float s = 0.f;
                const float* sp = SCp + (size_t)b * 64 + tid;
#pragma unroll 8
                for (int p = 0; p < NWG; ++p) s += sp[(size_t)p * 32 * 64];
                s = (mask[b * 64 + tid] > 0.f) ? s : -1e9f;
                float m = s;
#pragma unroll
                for (int d = 1; d < 64; d <<= 1) m = fmaxf(m, __shfl_xor(m, d));
                float e = __expf(s - m);
                float sum = e;
#pragma unroll
                for (int d = 1; d < 64; d <<= 1) sum += __shfl_xor(sum, d);
                s_af[tid] = e / sum;
            }
            __syncthreads();
            if (tid < 32) {
                a2l[tid] = (f16x2){(f16)s_af[2 * tid], (f16)s_af[2 * tid + 1]};
            }
            __syncthreads();
            // u1 = sum_s a_s * encWc[b][s][d]  (thread = d)
            float u1 = 0.f;
            {
                const f16* wp = encWcT + ((size_t)b * 512 + tid) * 64;
#pragma unroll
                for (int c = 0; c < 8; ++c) {
                    f16x8 ev = *(const f16x8*)(wp + c * 8);
#pragma unroll
                    for (int q = 0; q < 4; ++q) u1 = fdot2_(PAIR(ev, q), a2l[c * 4 + q], u1);
                }
            }
            float o = tanhf(u1 + u2 + bh[tid] + bc[tid]);
            x2n[(size_t)b * 1024 + tid] = (f16)o;
            obf[((size_t)b * 64 + t) * 512 + tid] = (__bf16)o;
        }

        gridbar(bar);
    }
}

extern "C" void kernel_launch(void* const* d_in, const int* in_sizes, int n_in,
                              void* d_out, int out_size, void* d_ws, size_t ws_size,
                              hipStream_t stream) {
    const int* trg = (const int*)d_in[0];
    const float* enc = (const float*)d_in[1];
    const float* init_h = (const float*)d_in[2];
    const float* mask = (const float*)d_in[3];
    const float* embW = (const float*)d_in[4];
    const float* Wih = (const float*)d_in[5];
    const float* Whh = (const float*)d_in[6];
    const float* bih = (const float*)d_in[7];
    const float* bhh = (const float*)d_in[8];
    const float* Wa = (const float*)d_in[9];
    const float* Wh = (const float*)d_in[10];
    const float* bh = (const float*)d_in[11];
    const float* Wc = (const float*)d_in[12];
    const float* bc = (const float*)d_in[13];
    const float* blog = (const float*)d_in[14];
    float* out = (float*)d_out;

    char* w = (char*)d_ws;
    auto alloc = [&](size_t bytes) { char* p = w; w += (bytes + 255) & ~(size_t)255; return p; };
    __bf16* embW_bf = (__bf16*)alloc((size_t)V_ * D_ * 2);
    __bf16* Wih_bf  = (__bf16*)alloc((size_t)G3_ * 1024 * 2);
    __bf16* Wa_bf   = (__bf16*)alloc((size_t)R_ * E_ * 2);
    __bf16* Wc_bf   = (__bf16*)alloc((size_t)D_ * E_ * 2);
    __bf16* enc_bf  = (__bf16*)alloc((size_t)BT_ * E_ * 2);
    __bf16* emb_bf  = (__bf16*)alloc((size_t)BT_ * D_ * 2);
    float* gxe      = (float*)alloc((size_t)T_ * G3_ * B_ * 4);
    float* encproj  = (float*)alloc((size_t)BT_ * R_ * 4);
    float* encWc    = (float*)alloc((size_t)BT_ * D_ * 4);
    f16* Wg         = (f16*)alloc((size_t)G3_ * 1024 * 2);
    f16* WhT        = (f16*)alloc((size_t)512 * 512 * 2);
    f16* encprojT   = (f16*)alloc((size_t)512 * 32 * 64 * 2);
    f16* encWcT     = (f16*)alloc((size_t)32 * 512 * 64 * 2);
    f16* x2         = (f16*)alloc((size_t)2 * 32 * 1024 * 2);
    float* hbuf     = (float*)alloc((size_t)2 * 32 * 512 * 4);
    float* Up       = (float*)alloc((size_t)NWG * 32 * 512 * 4);
    float* SCp      = (float*)alloc((size_t)NWG * 32 * 64 * 4);
    __bf16* o_bf    = (__bf16*)alloc((size_t)BT_ * D_ * 2);
    int* bar        = (int*)alloc(256);

    // 1) converts
    k_convert_bf16<<<(V_ * D_ / 8 + 255) / 256, 256, 0, stream>>>(embW, embW_bf, V_ * D_ / 8);
    k_convert_bf16<<<(G3_ * 1024 / 8 + 255) / 256, 256, 0, stream>>>(Wih, Wih_bf, G3_ * 1024 / 8);
    k_convert_bf16<<<(R_ * E_ / 8 + 255) / 256, 256, 0, stream>>>(Wa, Wa_bf, R_ * E_ / 8);
    k_convert_bf16<<<(D_ * E_ / 8 + 255) / 256, 256, 0, stream>>>(Wc, Wc_bf, D_ * E_ / 8);
    k_convert_bf16<<<(BT_ * E_ / 8 + 255) / 256, 256, 0, stream>>>(enc, enc_bf, BT_ * E_ / 8);

    // 2) gather embedding rows
    k_gather_emb<<<(BT_ * 64) / 256, 256, 0, stream>>>(trg, embW_bf, emb_bf);

    // 3) gx_emb = emb @ W_ih[:, :512]^T + b_ih -> [t][j][b]
    k_gemm_bf16<<<(BT_ / 128) * (G3_ / 128), 256, 0, stream>>>(
        emb_bf, Wih_bf, bih, gxe, BT_, G3_, 512, 512, 1024, 1);

    // 4) enc_proj = enc @ W_a^T; encWc = enc @ W_c^T
    k_gemm_bf16<<<(BT_ / 128) * (R_ / 128), 256, 0, stream>>>(
        enc_bf, Wa_bf, nullptr, encproj, BT_, R_, 512, 512, 512, 0);
    k_gemm_bf16<<<(BT_ / 128) * (D_ / 128), 256, 0, stream>>>(
        enc_bf, Wc_bf, nullptr, encWc, BT_, D_, 512, 512, 512, 0);

    // 5) pack weights / transposes / state
    k_pack_gates<<<(G3_ * 1024) / 256, 256, 0, stream>>>(Wih, Whh, Wg);
    k_pack_whT<<<(512 * 512) / 256, 256, 0, stream>>>(Wh, WhT);
    k_pack_epT<<<(512 * 32 * 64) / 256, 256, 0, stream>>>(encproj, encprojT);
    k_pack_ewT<<<(32 * 512 * 64) / 256, 256, 0, stream>>>(encWc, encWcT);
    k_init_state<<<(32 * 1024) / 256, 256, 0, stream>>>(init_h, x2, hbuf);
    (void)hipMemsetAsync(bar, 0, 8, stream);

    // 6) persistent recurrence
    k_recur<<<NWG, 512, 0, stream>>>(Wg, WhT, gxe, bhh, encprojT, encWcT, mask, bh, bc,
                                     x2, hbuf, Up, SCp, o_bf, bar);

    // 7) logits = o @ emb_W^T + b_logits
    k_gemm_bf16<<<(BT_ / 128) * (V_ / 128), 256, 0, stream>>>(
        o_bf, embW_bf, blog, out, BT_, V_, 512, 512, 512, 0);
}

// Round 6
// 2967.424 us; speedup vs baseline: 2.1963x; 2.1963x over previous
//
#include <hip/hip_runtime.h>

#define V_ 32000
#define D_ 512
#define R_ 512
#define E_ 512
#define B_ 32
#define T_ 64
#define S_ 64
#define BT_ (B_ * T_)   // 2048
#define G3_ (3 * R_)    // 1536
#define NWG 64          // persistent-kernel workgroups

typedef _Float16 f16;
typedef _Float16 f16x2 __attribute__((ext_vector_type(2)));
typedef _Float16 f16x4 __attribute__((ext_vector_type(4)));
typedef _Float16 f16x8 __attribute__((ext_vector_type(8)));
typedef __bf16 bf16x8 __attribute__((ext_vector_type(8)));
typedef float f32x4 __attribute__((ext_vector_type(4)));
typedef unsigned long long ull;

#define PAIR(v, i) (f16x2){(v)[2*(i)], (v)[2*(i)+1]}

__device__ __forceinline__ float fdot2_(f16x2 a, f16x2 b, float c) {
    return __builtin_amdgcn_fdot2(a, b, c, false);
}
__device__ __forceinline__ float sigmoidf_(float x) {
    return 1.0f / (1.0f + __expf(-x));
}
// device-coherent (agent-scope, RELAXED: no cache-maintenance) accesses
__device__ __forceinline__ ull cload8(const void* p) {
    return __hip_atomic_load((const ull*)p, __ATOMIC_RELAXED, __HIP_MEMORY_SCOPE_AGENT);
}
__device__ __forceinline__ void cstore4(void* p, unsigned v) {
    __hip_atomic_store((unsigned*)p, v, __ATOMIC_RELAXED, __HIP_MEMORY_SCOPE_AGENT);
}
__device__ __forceinline__ void cstoref(float* p, float v) {
    __hip_atomic_store(p, v, __ATOMIC_RELAXED, __HIP_MEMORY_SCOPE_AGENT);
}

// ---------------- fp32 -> bf16 convert ----------------
__global__ __launch_bounds__(256) void k_convert_bf16(const float* __restrict__ src,
                                                      __bf16* __restrict__ dst, int n8) {
    int i = blockIdx.x * 256 + threadIdx.x;
    if (i >= n8) return;
    float4 a = *(const float4*)&src[(size_t)i * 8];
    float4 b = *(const float4*)&src[(size_t)i * 8 + 4];
    bf16x8 o;
    o[0] = (__bf16)a.x; o[1] = (__bf16)a.y; o[2] = (__bf16)a.z; o[3] = (__bf16)a.w;
    o[4] = (__bf16)b.x; o[5] = (__bf16)b.y; o[6] = (__bf16)b.z; o[7] = (__bf16)b.w;
    *(bf16x8*)&dst[(size_t)i * 8] = o;
}

// ---------------- fp32 -> f16 convert ----------------
__global__ __launch_bounds__(256) void k_convert_f16(const float* __restrict__ src,
                                                     f16* __restrict__ dst, int n8) {
    int i = blockIdx.x * 256 + threadIdx.x;
    if (i >= n8) return;
    float4 a = *(const float4*)&src[(size_t)i * 8];
    float4 b = *(const float4*)&src[(size_t)i * 8 + 4];
    f16x8 o;
    o[0] = (f16)a.x; o[1] = (f16)a.y; o[2] = (f16)a.z; o[3] = (f16)a.w;
    o[4] = (f16)b.x; o[5] = (f16)b.y; o[6] = (f16)b.z; o[7] = (f16)b.w;
    *(f16x8*)&dst[(size_t)i * 8] = o;
}

// ---------------- gather embedding rows (bf16) ----------------
__global__ __launch_bounds__(256) void k_gather_emb(const int* __restrict__ trg,
                                                    const __bf16* __restrict__ embW,
                                                    __bf16* __restrict__ dst) {
    int id = blockIdx.x * 256 + threadIdx.x;
    int bt = id >> 6, c = id & 63;
    int tok = trg[bt];
    *(uint4*)&dst[(size_t)bt * 512 + c * 8] = *(const uint4*)&embW[(size_t)tok * 512 + c * 8];
}

// ---------------- bf16 MFMA GEMM: C = A[M,K] * B^T[N,K] (+bias) ----------------
__global__ __launch_bounds__(256) void k_gemm_bf16(const __bf16* __restrict__ A,
                                                   const __bf16* __restrict__ B,
                                                   const float* __restrict__ bias,
                                                   float* __restrict__ out,
                                                   int M, int N, int K, int lda, int ldb,
                                                   int mode) {
    __shared__ __bf16 lA[128 * 40];
    __shared__ __bf16 lB[128 * 40];
    const int Mt = M >> 7;
    const int mt = blockIdx.x % Mt, nt = blockIdx.x / Mt;
    const int m0 = mt << 7, n0 = nt << 7;
    const int tid = threadIdx.x;
    const int w = tid >> 6, ln = tid & 63;
    const int wm = w >> 1, wn = w & 1;

    f32x4 acc[4][4];
#pragma unroll
    for (int mi = 0; mi < 4; ++mi)
#pragma unroll
        for (int ni = 0; ni < 4; ++ni) acc[mi][ni] = (f32x4){0.f, 0.f, 0.f, 0.f};

    const int k0 = (ln >> 4) * 8, rr = ln & 15;

    for (int kk = 0; kk < K; kk += 32) {
        __syncthreads();
#pragma unroll
        for (int p = 0; p < 2; ++p) {
            int i = p * 256 + tid;
            int r = i >> 2, q = i & 3;
            *(uint4*)&lA[r * 40 + q * 8] = *(const uint4*)&A[(size_t)(m0 + r) * lda + kk + q * 8];
            *(uint4*)&lB[r * 40 + q * 8] = *(const uint4*)&B[(size_t)(n0 + r) * ldb + kk + q * 8];
        }
        __syncthreads();
        bf16x8 af[4], bf[4];
#pragma unroll
        for (int mi = 0; mi < 4; ++mi) af[mi] = *(bf16x8*)&lA[(wm * 64 + mi * 16 + rr) * 40 + k0];
#pragma unroll
        for (int ni = 0; ni < 4; ++ni) bf[ni] = *(bf16x8*)&lB[(wn * 64 + ni * 16 + rr) * 40 + k0];
#pragma unroll
        for (int mi = 0; mi < 4; ++mi)
#pragma unroll
            for (int ni = 0; ni < 4; ++ni)
                acc[mi][ni] = __builtin_amdgcn_mfma_f32_16x16x32_bf16(af[mi], bf[ni], acc[mi][ni], 0, 0, 0);
    }

    const int rq = ln >> 4;
#pragma unroll
    for (int mi = 0; mi < 4; ++mi) {
#pragma unroll
        for (int ni = 0; ni < 4; ++ni) {
            int col = n0 + wn * 64 + ni * 16 + rr;
            float bv = bias ? bias[col] : 0.f;
#pragma unroll
            for (int reg = 0; reg < 4; ++reg) {
                int row = m0 + wm * 64 + mi * 16 + rq * 4 + reg;
                float v = acc[mi][ni][reg] + bv;
                if (mode == 0) {
                    out[(size_t)row * N + col] = v;
                } else {
                    int bb = row >> 6, tt = row & 63;
                    out[((size_t)tt * G3_ + col) * B_ + bb] = v;
                }
            }
        }
    }
}

// ---------------- weight packing (one-time) ----------------
// Wg[j3][k] f16, k<512: Wih[j3][512+k] (o-part), k>=512: Whh[j3][k-512]
__global__ __launch_bounds__(256) void k_pack_gates(const float* __restrict__ Wih,
                                                    const float* __restrict__ Whh,
                                                    f16* __restrict__ Wg) {
    int idx = blockIdx.x * 256 + threadIdx.x;  // 1536*1024
    int j3 = idx >> 10, k = idx & 1023;
    float v = (k < 512) ? Wih[(size_t)j3 * 1024 + 512 + k] : Whh[(size_t)j3 * 512 + (k - 512)];
    Wg[idx] = (f16)v;
}
// encWcT[b][d][s] = encWc[(b*64+s)][d]
__global__ __launch_bounds__(256) void k_pack_ewT(const float* __restrict__ ew, f16* __restrict__ ewT) {
    int idx = blockIdx.x * 256 + threadIdx.x;  // 32*512*64
    int b = idx >> 15, d = (idx >> 6) & 511, s = idx & 63;
    ewT[idx] = (f16)ew[((size_t)b * 64 + s) * 512 + d];
}
// state init: of16[0]=0; hx[0]=hbuf[0]=init_h
__global__ __launch_bounds__(256) void k_init_state(const float* __restrict__ init_h,
                                                    f16* __restrict__ of16,
                                                    float* __restrict__ hx,
                                                    float* __restrict__ hbuf) {
    int idx = blockIdx.x * 256 + threadIdx.x;  // 32*512
    float v = init_h[idx];
    of16[idx] = (f16)0.f;
    hx[idx] = v;
    hbuf[idx] = v;
}

// ---------------- grid barrier: monotonic counter, RELAXED only ----------------
// No acquire/release (those emit L2 invalidate/writeback on CDNA4 and evict the
// L2-resident weights). Visibility of shared state is via agent-scope RELAXED
// atomic loads/stores (device-coherent point); each wave drains its own stores
// (s_waitcnt vmcnt(0)) before arrival.
__device__ __forceinline__ void gridbar(unsigned* bar, unsigned target) {
    asm volatile("s_waitcnt vmcnt(0)" ::: "memory");
    __syncthreads();
    if (threadIdx.x == 0) {
        __hip_atomic_fetch_add(bar, 1u, __ATOMIC_RELAXED, __HIP_MEMORY_SCOPE_AGENT);
        while (__hip_atomic_load(bar, __ATOMIC_RELAXED, __HIP_MEMORY_SCOPE_AGENT) < target)
            __builtin_amdgcn_s_sleep(2);
    }
    asm volatile("" ::: "memory");
    __syncthreads();
}

// ---------------- persistent recurrence ----------------
// 64 wgs x 512 thr. Phase A (all wgs): wg owns 8 j -> gates + h_new.
// Phase B (wgs 0..31, wg=b): scores/softmax/u1/u2/o directly from L2-resident
// epf16 (encproj f16), whf16 (W_h f16), encWcT.
__global__ __launch_bounds__(512, 2) void k_recur(
    const f16* __restrict__ Wg, const f16* __restrict__ whf16,
    const f16* __restrict__ epf16, const f16* __restrict__ encWcT,
    const float* __restrict__ gxe, const float* __restrict__ bhh,
    const float* __restrict__ mask, const float* __restrict__ bh, const float* __restrict__ bc,
    f16* of16, float* hx, float* __restrict__ hbuf,
    __bf16* __restrict__ obf, unsigned* bar) {
    __shared__ __align__(16) f16 x2l[32 * 1032];
    __shared__ float sc[64];
    __shared__ float s_af[64];
    __shared__ f16x2 a2l[32];
    f16* hl16 = x2l;  // phase-B alias (1 KB)

    const int tid = threadIdx.x;
    const int wgid = blockIdx.x;
    const int bA = tid & 31;
    const int half = (tid >> 5) & 1;
    const int jl = tid >> 6;
    const int j = wgid * 8 + jl;

    for (int t = 0; t < T_; ++t) {
        const int cur = t & 1, nxt = cur ^ 1;
        const f16* oc = of16 + (size_t)cur * 32 * 512;
        const float* hc = hx + (size_t)cur * 32 * 512;
        f16* on = of16 + (size_t)nxt * 32 * 512;
        float* hn_ = hx + (size_t)nxt * 32 * 512;
        const float* hsrc = hbuf + (size_t)cur * 32 * 512;
        float* hdst = hbuf + (size_t)nxt * 32 * 512;
        const float* gp = gxe + (size_t)t * G3_ * B_;

        // ---- stage x = [o_prev(f16) | h_prev(f32->f16)] into LDS rows of 1032 ----
#pragma unroll
        for (int i = 0; i < 8; ++i) {
            int f = tid + i * 512;                 // 4096 chunks of 4 f16
            int row = f >> 7, col = f & 127;
            ull v = cload8(oc + (size_t)f * 4);
            *(ull*)(x2l + row * 1032 + col * 4) = v;
        }
#pragma unroll
        for (int i = 0; i < 16; ++i) {
            int f = tid + i * 512;                 // 8192 chunks of 2 f32
            int row = f >> 8, col = f & 255;
            ull v = cload8(hc + (size_t)f * 2);
            float2 fv; __builtin_memcpy(&fv, &v, 8);
            f16x2 hv = {(f16)fv.x, (f16)fv.y};
            *(f16x2*)(x2l + row * 1032 + 512 + col * 2) = hv;
        }
        __syncthreads();

        // ---- A1: gates + h_new ----
        {
            const f16* xb = x2l + bA * 1032 + half * 512;
            const f16* wr = Wg + (size_t)(j) * 1024 + half * 512;
            const f16* wz = Wg + (size_t)(512 + j) * 1024 + half * 512;
            const f16* wn = Wg + (size_t)(1024 + j) * 1024 + half * 512;
            float ar = 0.f, az = 0.f, an = 0.f;
#pragma unroll 4
            for (int c = 0; c < 64; ++c) {
                f16x8 xv = *(const f16x8*)(xb + c * 8);
                f16x8 wrv = *(const f16x8*)(wr + c * 8);
                f16x8 wzv = *(const f16x8*)(wz + c * 8);
                f16x8 wnv = *(const f16x8*)(wn + c * 8);
#pragma unroll
                for (int q = 0; q < 4; ++q) {
                    f16x2 xp = PAIR(xv, q);
                    ar = fdot2_(xp, PAIR(wrv, q), ar);
                    az = fdot2_(xp, PAIR(wzv, q), az);
                    an = fdot2_(xp, PAIR(wnv, q), an);
                }
            }
            float aro = __shfl_xor(ar, 32);
            float azo = __shfl_xor(az, 32);
            float ano = __shfl_xor(an, 32);
            float gr = gp[(size_t)j * 32 + bA];
            float gz = gp[(size_t)(512 + j) * 32 + bA];
            float gn = gp[(size_t)(1024 + j) * 32 + bA];
            float rpre = gr + bhh[j] + ar + aro;
            float zpre = gz + bhh[512 + j] + az + azo;
            float r = sigmoidf_(rpre);
            float z = sigmoidf_(zpre);
            float gxn = gn + (half ? ano : an);
            float ghn = bhh[1024 + j] + (half ? an : ano);
            float n = tanhf(gxn + r * ghn);
            float hp = hsrc[(size_t)bA * 512 + j];
            float hnew = (1.f - z) * n + z * hp;
            if (half == 0) {
                hdst[(size_t)bA * 512 + j] = hnew;      // own-wg copy (cached)
                cstoref(hn_ + (size_t)bA * 512 + j, hnew);  // coherent publish
            }
        }

        gridbar(bar, (unsigned)(2 * t + 1) * NWG);

        // ---- Phase B (wg = b): scores + softmax + output ----
        if (wgid < 32) {
            const int b = wgid;
            if (tid < 256) {
                ull v = cload8(hn_ + (size_t)b * 512 + tid * 2);
                float2 fv; __builtin_memcpy(&fv, &v, 8);
                f16x2 hv = {(f16)fv.x, (f16)fv.y};
                *(f16x2*)(hl16 + tid * 2) = hv;
            }
            __syncthreads();
            // scores: s = tid>>3, q = tid&7 (64B chunk each)
            {
                int s = tid >> 3, q = tid & 7;
                const f16* ep = epf16 + ((size_t)(b * 64 + s)) * 512 + q * 64;
                const f16* hh = hl16 + q * 64;
                float a = 0.f;
#pragma unroll
                for (int c = 0; c < 8; ++c) {
                    f16x8 ev = *(const f16x8*)(ep + c * 8);
                    f16x8 xv = *(const f16x8*)(hh + c * 8);
#pragma unroll
                    for (int qq = 0; qq < 4; ++qq) a = fdot2_(PAIR(ev, qq), PAIR(xv, qq), a);
                }
                a += __shfl_xor(a, 1);
                a += __shfl_xor(a, 2);
                a += __shfl_xor(a, 4);
                if (q == 0) sc[s] = a;
            }
            __syncthreads();
            if (tid < 64) {
                float s = sc[tid];
                s = (mask[b * 64 + tid] > 0.f) ? s : -1e9f;
                float m = s;
#pragma unroll
                for (int d = 1; d < 64; d <<= 1) m = fmaxf(m, __shfl_xor(m, d));
                float e = __expf(s - m);
                float sum = e;
#pragma unroll
                for (int d = 1; d < 64; d <<= 1) sum += __shfl_xor(sum, d);
                s_af[tid] = e / sum;
            }
            __syncthreads();
            if (tid < 32) {
                a2l[tid] = (f16x2){(f16)s_af[2 * tid], (f16)s_af[2 * tid + 1]};
            }
            __syncthreads();
            // u = b_h + b_c + Wh[d]·h + sum_s a_s encWc[b][s][d];  d = tid
            {
                const int d = tid;
                float u = bh[d] + bc[d];
                const f16* wrow = whf16 + (size_t)d * 512;
#pragma unroll 8
                for (int c = 0; c < 64; ++c) {
                    f16x8 wv = *(const f16x8*)(wrow + c * 8);
                    f16x8 xv = *(const f16x8*)(hl16 + c * 8);
#pragma unroll
                    for (int qq = 0; qq < 4; ++qq) u = fdot2_(PAIR(wv, qq), PAIR(xv, qq), u);
                }
                const f16* ew = encWcT + ((size_t)b * 512 + d) * 64;
#pragma unroll
                for (int c = 0; c < 8; ++c) {
                    f16x8 ev = *(const f16x8*)(ew + c * 8);
#pragma unroll
                    for (int qq = 0; qq < 4; ++qq) u = fdot2_(PAIR(ev, qq), a2l[c * 4 + qq], u);
                }
                float o = tanhf(u);
                obf[((size_t)b * 64 + t) * 512 + d] = (__bf16)o;
                float o2 = __shfl_xor(o, 1);
                if ((tid & 1) == 0) {
                    f16x2 pv = {(f16)o, (f16)o2};
                    unsigned uv; __builtin_memcpy(&uv, &pv, 4);
                    cstore4(on + (size_t)b * 512 + d, uv);  // coherent publish o
                }
            }
        }

        gridbar(bar, (unsigned)(2 * t + 2) * NWG);
    }
}

extern "C" void kernel_launch(void* const* d_in, const int* in_sizes, int n_in,
                              void* d_out, int out_size, void* d_ws, size_t ws_size,
                              hipStream_t stream) {
    const int* trg = (const int*)d_in[0];
    const float* enc = (const float*)d_in[1];
    const float* init_h = (const float*)d_in[2];
    const float* mask = (const float*)d_in[3];
    const float* embW = (const float*)d_in[4];
    const float* Wih = (const float*)d_in[5];
    const float* Whh = (const float*)d_in[6];
    const float* bih = (const float*)d_in[7];
    const float* bhh = (const float*)d_in[8];
    const float* Wa = (const float*)d_in[9];
    const float* Wh = (const float*)d_in[10];
    const float* bh = (const float*)d_in[11];
    const float* Wc = (const float*)d_in[12];
    const float* bc = (const float*)d_in[13];
    const float* blog = (const float*)d_in[14];
    float* out = (float*)d_out;

    char* w = (char*)d_ws;
    auto alloc = [&](size_t bytes) { char* p = w; w += (bytes + 255) & ~(size_t)255; return p; };
    __bf16* embW_bf = (__bf16*)alloc((size_t)V_ * D_ * 2);
    __bf16* Wih_bf  = (__bf16*)alloc((size_t)G3_ * 1024 * 2);
    __bf16* Wa_bf   = (__bf16*)alloc((size_t)R_ * E_ * 2);
    __bf16* Wc_bf   = (__bf16*)alloc((size_t)D_ * E_ * 2);
    __bf16* enc_bf  = (__bf16*)alloc((size_t)BT_ * E_ * 2);
    __bf16* emb_bf  = (__bf16*)alloc((size_t)BT_ * D_ * 2);
    float* gxe      = (float*)alloc((size_t)T_ * G3_ * B_ * 4);
    float* encproj  = (float*)alloc((size_t)BT_ * R_ * 4);
    float* encWc    = (float*)alloc((size_t)BT_ * D_ * 4);
    f16* Wg         = (f16*)alloc((size_t)G3_ * 1024 * 2);
    f16* whf16      = (f16*)alloc((size_t)512 * 512 * 2);
    f16* epf16      = (f16*)alloc((size_t)BT_ * 512 * 2);
    f16* encWcT     = (f16*)alloc((size_t)32 * 512 * 64 * 2);
    f16* of16       = (f16*)alloc((size_t)2 * 32 * 512 * 2);
    float* hx       = (float*)alloc((size_t)2 * 32 * 512 * 4);
    float* hbuf     = (float*)alloc((size_t)2 * 32 * 512 * 4);
    __bf16* o_bf    = (__bf16*)alloc((size_t)BT_ * D_ * 2);
    unsigned* bar   = (unsigned*)alloc(256);

    // 1) converts
    k_convert_bf16<<<(V_ * D_ / 8 + 255) / 256, 256, 0, stream>>>(embW, embW_bf, V_ * D_ / 8);
    k_convert_bf16<<<(G3_ * 1024 / 8 + 255) / 256, 256, 0, stream>>>(Wih, Wih_bf, G3_ * 1024 / 8);
    k_convert_bf16<<<(R_ * E_ / 8 + 255) / 256, 256, 0, stream>>>(Wa, Wa_bf, R_ * E_ / 8);
    k_convert_bf16<<<(D_ * E_ / 8 + 255) / 256, 256, 0, stream>>>(Wc, Wc_bf, D_ * E_ / 8);
    k_convert_bf16<<<(BT_ * E_ / 8 + 255) / 256, 256, 0, stream>>>(enc, enc_bf, BT_ * E_ / 8);

    // 2) gather embedding rows
    k_gather_emb<<<(BT_ * 64) / 256, 256, 0, stream>>>(trg, embW_bf, emb_bf);

    // 3) gx_emb = emb @ W_ih[:, :512]^T + b_ih -> [t][j][b]
    k_gemm_bf16<<<(BT_ / 128) * (G3_ / 128), 256, 0, stream>>>(
        emb_bf, Wih_bf, bih, gxe, BT_, G3_, 512, 512, 1024, 1);

    // 4) enc_proj = enc @ W_a^T; encWc = enc @ W_c^T
    k_gemm_bf16<<<(BT_ / 128) * (R_ / 128), 256, 0, stream>>>(
        enc_bf, Wa_bf, nullptr, encproj, BT_, R_, 512, 512, 512, 0);
    k_gemm_bf16<<<(BT_ / 128) * (D_ / 128), 256, 0, stream>>>(
        enc_bf, Wc_bf, nullptr, encWc, BT_, D_, 512, 512, 512, 0);

    // 5) pack weights / state
    k_pack_gates<<<(G3_ * 1024) / 256, 256, 0, stream>>>(Wih, Whh, Wg);
    k_convert_f16<<<(512 * 512 / 8 + 255) / 256, 256, 0, stream>>>(Wh, whf16, 512 * 512 / 8);
    k_convert_f16<<<(BT_ * 512 / 8 + 255) / 256, 256, 0, stream>>>(encproj, epf16, BT_ * 512 / 8);
    k_pack_ewT<<<(32 * 512 * 64) / 256, 256, 0, stream>>>(encWc, encWcT);
    k_init_state<<<(32 * 512) / 256, 256, 0, stream>>>(init_h, of16, hx, hbuf);
    (void)hipMemsetAsync(bar, 0, 8, stream);

    // 6) persistent recurrence
    k_recur<<<NWG, 512, 0, stream>>>(Wg, whf16, epf16, encWcT, gxe, bhh, mask, bh, bc,
                                     of16, hx, hbuf, o_bf, bar);

    // 7) logits = o @ emb_W^T + b_logits
    k_gemm_bf16<<<(BT_ / 128) * (V_ / 128), 256, 0, stream>>>(
        o_bf, embW_bf, blog, out, BT_, V_, 512, 512, 512, 0);
}

// Round 9
// 2734.819 us; speedup vs baseline: 2.3831x; 1.0851x over previous
//
#include <hip/hip_runtime.h>

#define V_ 32000
#define D_ 512
#define R_ 512
#define E_ 512
#define B_ 32
#define T_ 64
#define S_ 64
#define BT_ (B_ * T_)   // 2048
#define G3_ (3 * R_)    // 1536
#define NWG 64          // persistent-kernel workgroups

typedef _Float16 f16;
typedef _Float16 f16x2 __attribute__((ext_vector_type(2)));
typedef _Float16 f16x4 __attribute__((ext_vector_type(4)));
typedef _Float16 f16x8 __attribute__((ext_vector_type(8)));
typedef __bf16 bf16x8 __attribute__((ext_vector_type(8)));
typedef float f32x4 __attribute__((ext_vector_type(4)));
typedef unsigned long long ull;

#define PAIR(v, i) (f16x2){(v)[2*(i)], (v)[2*(i)+1]}

__device__ __forceinline__ float fdot2_(f16x2 a, f16x2 b, float c) {
    return __builtin_amdgcn_fdot2(a, b, c, false);
}
__device__ __forceinline__ float sigmoidf_(float x) {
    return 1.0f / (1.0f + __expf(-x));
}

// ---------------- fp32 -> bf16 convert ----------------
__global__ __launch_bounds__(256) void k_convert_bf16(const float* __restrict__ src,
                                                      __bf16* __restrict__ dst, int n8) {
    int i = blockIdx.x * 256 + threadIdx.x;
    if (i >= n8) return;
    float4 a = *(const float4*)&src[(size_t)i * 8];
    float4 b = *(const float4*)&src[(size_t)i * 8 + 4];
    bf16x8 o;
    o[0] = (__bf16)a.x; o[1] = (__bf16)a.y; o[2] = (__bf16)a.z; o[3] = (__bf16)a.w;
    o[4] = (__bf16)b.x; o[5] = (__bf16)b.y; o[6] = (__bf16)b.z; o[7] = (__bf16)b.w;
    *(bf16x8*)&dst[(size_t)i * 8] = o;
}

// ---------------- fp32 -> f16 convert ----------------
__global__ __launch_bounds__(256) void k_convert_f16(const float* __restrict__ src,
                                                     f16* __restrict__ dst, int n8) {
    int i = blockIdx.x * 256 + threadIdx.x;
    if (i >= n8) return;
    float4 a = *(const float4*)&src[(size_t)i * 8];
    float4 b = *(const float4*)&src[(size_t)i * 8 + 4];
    f16x8 o;
    o[0] = (f16)a.x; o[1] = (f16)a.y; o[2] = (f16)a.z; o[3] = (f16)a.w;
    o[4] = (f16)b.x; o[5] = (f16)b.y; o[6] = (f16)b.z; o[7] = (f16)b.w;
    *(f16x8*)&dst[(size_t)i * 8] = o;
}

// ---------------- gather embedding rows (bf16) ----------------
__global__ __launch_bounds__(256) void k_gather_emb(const int* __restrict__ trg,
                                                    const __bf16* __restrict__ embW,
                                                    __bf16* __restrict__ dst) {
    int id = blockIdx.x * 256 + threadIdx.x;
    int bt = id >> 6, c = id & 63;
    int tok = trg[bt];
    *(uint4*)&dst[(size_t)bt * 512 + c * 8] = *(const uint4*)&embW[(size_t)tok * 512 + c * 8];
}

// ---------------- bf16 MFMA GEMM: C = A[M,K] * B^T[N,K] (+bias) ----------------
__global__ __launch_bounds__(256) void k_gemm_bf16(const __bf16* __restrict__ A,
                                                   const __bf16* __restrict__ B,
                                                   const float* __restrict__ bias,
                                                   float* __restrict__ out,
                                                   int M, int N, int K, int lda, int ldb,
                                                   int mode) {
    __shared__ __bf16 lA[128 * 40];
    __shared__ __bf16 lB[128 * 40];
    const int Mt = M >> 7;
    const int mt = blockIdx.x % Mt, nt = blockIdx.x / Mt;
    const int m0 = mt << 7, n0 = nt << 7;
    const int tid = threadIdx.x;
    const int w = tid >> 6, ln = tid & 63;
    const int wm = w >> 1, wn = w & 1;

    f32x4 acc[4][4];
#pragma unroll
    for (int mi = 0; mi < 4; ++mi)
#pragma unroll
        for (int ni = 0; ni < 4; ++ni) acc[mi][ni] = (f32x4){0.f, 0.f, 0.f, 0.f};

    const int k0 = (ln >> 4) * 8, rr = ln & 15;

    for (int kk = 0; kk < K; kk += 32) {
        __syncthreads();
#pragma unroll
        for (int p = 0; p < 2; ++p) {
            int i = p * 256 + tid;
            int r = i >> 2, q = i & 3;
            *(uint4*)&lA[r * 40 + q * 8] = *(const uint4*)&A[(size_t)(m0 + r) * lda + kk + q * 8];
            *(uint4*)&lB[r * 40 + q * 8] = *(const uint4*)&B[(size_t)(n0 + r) * ldb + kk + q * 8];
        }
        __syncthreads();
        bf16x8 af[4], bf[4];
#pragma unroll
        for (int mi = 0; mi < 4; ++mi) af[mi] = *(bf16x8*)&lA[(wm * 64 + mi * 16 + rr) * 40 + k0];
#pragma unroll
        for (int ni = 0; ni < 4; ++ni) bf[ni] = *(bf16x8*)&lB[(wn * 64 + ni * 16 + rr) * 40 + k0];
#pragma unroll
        for (int mi = 0; mi < 4; ++mi)
#pragma unroll
            for (int ni = 0; ni < 4; ++ni)
                acc[mi][ni] = __builtin_amdgcn_mfma_f32_16x16x32_bf16(af[mi], bf[ni], acc[mi][ni], 0, 0, 0);
    }

    const int rq = ln >> 4;
#pragma unroll
    for (int mi = 0; mi < 4; ++mi) {
#pragma unroll
        for (int ni = 0; ni < 4; ++ni) {
            int col = n0 + wn * 64 + ni * 16 + rr;
            float bv = bias ? bias[col] : 0.f;
#pragma unroll
            for (int reg = 0; reg < 4; ++reg) {
                int row = m0 + wm * 64 + mi * 16 + rq * 4 + reg;
                float v = acc[mi][ni][reg] + bv;
                if (mode == 0) {
                    out[(size_t)row * N + col] = v;
                } else {
                    int bb = row >> 6, tt = row & 63;
                    out[((size_t)tt * G3_ + col) * B_ + bb] = v;
                }
            }
        }
    }
}

// ---------------- weight packing (one-time) ----------------
__global__ __launch_bounds__(256) void k_pack_gates(const float* __restrict__ Wih,
                                                    const float* __restrict__ Whh,
                                                    f16* __restrict__ Wg) {
    int idx = blockIdx.x * 256 + threadIdx.x;  // 1536*1024
    int j3 = idx >> 10, k = idx & 1023;
    float v = (k < 512) ? Wih[(size_t)j3 * 1024 + 512 + k] : Whh[(size_t)j3 * 512 + (k - 512)];
    Wg[idx] = (f16)v;
}
__global__ __launch_bounds__(256) void k_pack_ewT(const float* __restrict__ ew, f16* __restrict__ ewT) {
    int idx = blockIdx.x * 256 + threadIdx.x;  // 32*512*64
    int b = idx >> 15, d = (idx >> 6) & 511, s = idx & 63;
    ewT[idx] = (f16)ew[((size_t)b * 64 + s) * 512 + d];
}
// x16[0] = [o=0(0..511) | h=init_h(512..1023)] f16 per b; hbuf[0] = init_h f32
__global__ __launch_bounds__(256) void k_init_state(const float* __restrict__ init_h,
                                                    f16* __restrict__ x16,
                                                    float* __restrict__ hbuf) {
    int idx = blockIdx.x * 256 + threadIdx.x;  // 32*1024
    int b = idx >> 10, k = idx & 1023;
    if (k < 512) {
        x16[idx] = (f16)0.f;
    } else {
        float v = init_h[(size_t)b * 512 + (k - 512)];
        x16[idx] = (f16)v;
        hbuf[(size_t)b * 512 + (k - 512)] = v;
    }
}

// ---------------- grid barrier: monotonic counter, RELAXED only ----------------
__device__ __forceinline__ void gridbar(unsigned* bar, unsigned target) {
    asm volatile("s_waitcnt vmcnt(0)" ::: "memory");
    __syncthreads();
    if (threadIdx.x == 0) {
        __hip_atomic_fetch_add(bar, 1u, __ATOMIC_RELAXED, __HIP_MEMORY_SCOPE_AGENT);
        while (__hip_atomic_load(bar, __ATOMIC_RELAXED, __HIP_MEMORY_SCOPE_AGENT) < target)
            __builtin_amdgcn_s_sleep(1);
    }
    asm volatile("" ::: "memory");
    __syncthreads();
}

// ---------------- persistent recurrence ----------------
// State x16[2][32][1024] f16 ([o|h] per b). Staging/publish via batched inline-asm
// sc0 sc1 (device-coherent) loads/stores — pipelined, drained once per phase.
// Asm load outputs are EARLY-CLOBBER (=&v): dst must not alias later addr regs.
// LDS rows are 1024 f16 = 128 uint4 wide -> flat uint4 idx f: row=f>>7, col=f&127.
__global__ __launch_bounds__(512, 2) void k_recur(
    const f16* __restrict__ Wg, const f16* __restrict__ whf16,
    const f16* __restrict__ epf16, const f16* __restrict__ encWcT,
    const float* __restrict__ gxe, const float* __restrict__ bhh,
    const float* __restrict__ mask, const float* __restrict__ bh, const float* __restrict__ bc,
    f16* x16, float* __restrict__ hbuf,
    __bf16* __restrict__ obf, unsigned* bar) {
    __shared__ __align__(16) f16 x2l[32 * 1032];
    __shared__ __align__(16) f16 hl16[512];
    __shared__ float sc[64];
    __shared__ float s_af[64];
    __shared__ f16x2 a2l[32];

    const int tid = threadIdx.x;
    const int wgid = blockIdx.x;
    const int bA = tid & 31;
    const int half = (tid >> 5) & 1;
    const int jl = tid >> 6;
    const int j = wgid * 8 + jl;

    for (int t = 0; t < T_; ++t) {
        const int cur = t & 1, nxt = cur ^ 1;
        const f16* x2c = x16 + (size_t)cur * 32 * 1024;
        f16* x2n = x16 + (size_t)nxt * 32 * 1024;
        const float* hsrc = hbuf + (size_t)cur * 32 * 512;
        float* hdst = hbuf + (size_t)nxt * 32 * 512;
        const float* gp = gxe + (size_t)t * G3_ * B_;

        // ---- stage x16[cur] (64KB) into LDS: 8 batched coherent 16B loads/thread ----
        {
            uint64_t ab = (uint64_t)(const void*)x2c + (uint64_t)tid * 16;
            uint4 r0, r1, r2, r3, r4, r5, r6, r7;
            asm volatile(
                "global_load_dwordx4 %0, %8, off sc0 sc1\n\t"
                "global_load_dwordx4 %1, %9, off sc0 sc1\n\t"
                "global_load_dwordx4 %2, %10, off sc0 sc1\n\t"
                "global_load_dwordx4 %3, %11, off sc0 sc1\n\t"
                "global_load_dwordx4 %4, %12, off sc0 sc1\n\t"
                "global_load_dwordx4 %5, %13, off sc0 sc1\n\t"
                "global_load_dwordx4 %6, %14, off sc0 sc1\n\t"
                "global_load_dwordx4 %7, %15, off sc0 sc1\n\t"
                "s_waitcnt vmcnt(0)"
                : "=&v"(r0), "=&v"(r1), "=&v"(r2), "=&v"(r3),
                  "=&v"(r4), "=&v"(r5), "=&v"(r6), "=&v"(r7)
                : "v"(ab), "v"(ab + 8192), "v"(ab + 16384), "v"(ab + 24576),
                  "v"(ab + 32768), "v"(ab + 40960), "v"(ab + 49152), "v"(ab + 57344)
                : "memory");
#define STORE_CHUNK(i, r) { int f = tid + (i) * 512; int row = f >> 7, col = f & 127; \
                            *(uint4*)(x2l + row * 1032 + col * 8) = (r); }
            STORE_CHUNK(0, r0) STORE_CHUNK(1, r1) STORE_CHUNK(2, r2) STORE_CHUNK(3, r3)
            STORE_CHUNK(4, r4) STORE_CHUNK(5, r5) STORE_CHUNK(6, r6) STORE_CHUNK(7, r7)
#undef STORE_CHUNK
        }
        __syncthreads();

        // ---- A1: gates + h_new ----
        {
            const f16* xb = x2l + bA * 1032 + half * 512;
            const f16* wr = Wg + (size_t)(j) * 1024 + half * 512;
            const f16* wz = Wg + (size_t)(512 + j) * 1024 + half * 512;
            const f16* wn = Wg + (size_t)(1024 + j) * 1024 + half * 512;
            float ar = 0.f, az = 0.f, an = 0.f;
#pragma unroll 4
            for (int c = 0; c < 64; ++c) {
                f16x8 xv = *(const f16x8*)(xb + c * 8);
                f16x8 wrv = *(const f16x8*)(wr + c * 8);
                f16x8 wzv = *(const f16x8*)(wz + c * 8);
                f16x8 wnv = *(const f16x8*)(wn + c * 8);
#pragma unroll
                for (int q = 0; q < 4; ++q) {
                    f16x2 xp = PAIR(xv, q);
                    ar = fdot2_(xp, PAIR(wrv, q), ar);
                    az = fdot2_(xp, PAIR(wzv, q), az);
                    an = fdot2_(xp, PAIR(wnv, q), an);
                }
            }
            float aro = __shfl_xor(ar, 32);
            float azo = __shfl_xor(az, 32);
            float ano = __shfl_xor(an, 32);
            float gr = gp[(size_t)j * 32 + bA];
            float gz = gp[(size_t)(512 + j) * 32 + bA];
            float gn = gp[(size_t)(1024 + j) * 32 + bA];
            float rpre = gr + bhh[j] + ar + aro;
            float zpre = gz + bhh[512 + j] + az + azo;
            float r = sigmoidf_(rpre);
            float z = sigmoidf_(zpre);
            float gxn = gn + (half ? ano : an);
            float ghn = bhh[1024 + j] + (half ? an : ano);
            float n = tanhf(gxn + r * ghn);
            float hp = hsrc[(size_t)bA * 512 + j];
            float hnew = (1.f - z) * n + z * hp;
            if (half == 0) {
                hdst[(size_t)bA * 512 + j] = hnew;         // own-wg f32 copy (cached)
                f16 h16 = (f16)hnew;
                unsigned short us; __builtin_memcpy(&us, &h16, 2);
                unsigned hv = us;
                uint64_t a = (uint64_t)(void*)x2n + (uint64_t)(bA * 2048 + 1024 + j * 2);
                asm volatile("global_store_short %0, %1, off sc0 sc1" :: "v"(a), "v"(hv) : "memory");
            }
        }

        gridbar(bar, (unsigned)(2 * t + 1) * NWG);

        // ---- Phase B (wg = b): scores + softmax + output ----
        if (wgid < 32) {
            const int b = wgid;
            if (tid < 64) {
                uint64_t a = (uint64_t)(void*)x2n + (uint64_t)(b * 2048 + 1024) + (uint64_t)tid * 16;
                uint4 r;
                asm volatile("global_load_dwordx4 %0, %1, off sc0 sc1\n\t"
                             "s_waitcnt vmcnt(0)"
                             : "=&v"(r) : "v"(a) : "memory");
                *(uint4*)(hl16 + tid * 8) = r;
            }
            __syncthreads();
            // scores: s = tid>>3, q = tid&7
            {
                int s = tid >> 3, q = tid & 7;
                const f16* ep = epf16 + ((size_t)(b * 64 + s)) * 512 + q * 64;
                const f16* hh = hl16 + q * 64;
                float a = 0.f;
#pragma unroll
                for (int c = 0; c < 8; ++c) {
                    f16x8 ev = *(const f16x8*)(ep + c * 8);
                    f16x8 xv = *(const f16x8*)(hh + c * 8);
#pragma unroll
                    for (int qq = 0; qq < 4; ++qq) a = fdot2_(PAIR(ev, qq), PAIR(xv, qq), a);
                }
                a += __shfl_xor(a, 1);
                a += __shfl_xor(a, 2);
                a += __shfl_xor(a, 4);
                if (q == 0) sc[s] = a;
            }
            __syncthreads();
            if (tid < 64) {
                float s = sc[tid];
                s = (mask[b * 64 + tid] > 0.f) ? s : -1e9f;
                float m = s;
#pragma unroll
                for (int d = 1; d < 64; d <<= 1) m = fmaxf(m, __shfl_xor(m, d));
                float e = __expf(s - m);
                float sum = e;
#pragma unroll
                for (int d = 1; d < 64; d <<= 1) sum += __shfl_xor(sum, d);
                s_af[tid] = e / sum;
            }
            __syncthreads();
            if (tid < 32) {
                a2l[tid] = (f16x2){(f16)s_af[2 * tid], (f16)s_af[2 * tid + 1]};
            }
            __syncthreads();
            // u = b_h + b_c + Wh[d]·h + sum_s a_s encWc[b][s][d];  d = tid
            {
                const int d = tid;
                float u = bh[d] + bc[d];
                const f16* wrow = whf16 + (size_t)d * 512;
#pragma unroll 8
                for (int c = 0; c < 64; ++c) {
                    f16x8 wv = *(const f16x8*)(wrow + c * 8);
                    f16x8 xv = *(const f16x8*)(hl16 + c * 8);
#pragma unroll
                    for (int qq = 0; qq < 4; ++qq) u = fdot2_(PAIR(wv, qq), PAIR(xv, qq), u);
                }
                const f16* ew = encWcT + ((size_t)b * 512 + d) * 64;
#pragma unroll
                for (int c = 0; c < 8; ++c) {
                    f16x8 ev = *(const f16x8*)(ew + c * 8);
#pragma unroll
                    for (int qq = 0; qq < 4; ++qq) u = fdot2_(PAIR(ev, qq), a2l[c * 4 + qq], u);
                }
                float o = tanhf(u);
                obf[((size_t)b * 64 + t) * 512 + d] = (__bf16)o;
                float o2 = __shfl_xor(o, 1);
                if ((tid & 1) == 0) {
                    f16x2 pv = {(f16)o, (f16)o2};
                    unsigned uv; __builtin_memcpy(&uv, &pv, 4);
                    uint64_t a = (uint64_t)(void*)x2n + (uint64_t)(b * 2048 + d * 2);
                    asm volatile("global_store_dword %0, %1, off sc0 sc1" :: "v"(a), "v"(uv) : "memory");
                }
            }
        }

        gridbar(bar, (unsigned)(2 * t + 2) * NWG);
    }
}

extern "C" void kernel_launch(void* const* d_in, const int* in_sizes, int n_in,
                              void* d_out, int out_size, void* d_ws, size_t ws_size,
                              hipStream_t stream) {
    const int* trg = (const int*)d_in[0];
    const float* enc = (const float*)d_in[1];
    const float* init_h = (const float*)d_in[2];
    const float* mask = (const float*)d_in[3];
    const float* embW = (const float*)d_in[4];
    const float* Wih = (const float*)d_in[5];
    const float* Whh = (const float*)d_in[6];
    const float* bih = (const float*)d_in[7];
    const float* bhh = (const float*)d_in[8];
    const float* Wa = (const float*)d_in[9];
    const float* Wh = (const float*)d_in[10];
    const float* bh = (const float*)d_in[11];
    const float* Wc = (const float*)d_in[12];
    const float* bc = (const float*)d_in[13];
    const float* blog = (const float*)d_in[14];
    float* out = (float*)d_out;

    char* w = (char*)d_ws;
    auto alloc = [&](size_t bytes) { char* p = w; w += (bytes + 255) & ~(size_t)255; return p; };
    __bf16* embW_bf = (__bf16*)alloc((size_t)V_ * D_ * 2);
    __bf16* Wih_bf  = (__bf16*)alloc((size_t)G3_ * 1024 * 2);
    __bf16* Wa_bf   = (__bf16*)alloc((size_t)R_ * E_ * 2);
    __bf16* Wc_bf   = (__bf16*)alloc((size_t)D_ * E_ * 2);
    __bf16* enc_bf  = (__bf16*)alloc((size_t)BT_ * E_ * 2);
    __bf16* emb_bf  = (__bf16*)alloc((size_t)BT_ * D_ * 2);
    float* gxe      = (float*)alloc((size_t)T_ * G3_ * B_ * 4);
    float* encproj  = (float*)alloc((size_t)BT_ * R_ * 4);
    float* encWc    = (float*)alloc((size_t)BT_ * D_ * 4);
    f16* Wg         = (f16*)alloc((size_t)G3_ * 1024 * 2);
    f16* whf16      = (f16*)alloc((size_t)512 * 512 * 2);
    f16* epf16      = (f16*)alloc((size_t)BT_ * 512 * 2);
    f16* encWcT     = (f16*)alloc((size_t)32 * 512 * 64 * 2);
    f16* x16        = (f16*)alloc((size_t)2 * 32 * 1024 * 2);
    float* hbuf     = (float*)alloc((size_t)2 * 32 * 512 * 4);
    __bf16* o_bf    = (__bf16*)alloc((size_t)BT_ * D_ * 2);
    unsigned* bar   = (unsigned*)alloc(256);

    // 1) converts
    k_convert_bf16<<<(V_ * D_ / 8 + 255) / 256, 256, 0, stream>>>(embW, embW_bf, V_ * D_ / 8);
    k_convert_bf16<<<(G3_ * 1024 / 8 + 255) / 256, 256, 0, stream>>>(Wih, Wih_bf, G3_ * 1024 / 8);
    k_convert_bf16<<<(R_ * E_ / 8 + 255) / 256, 256, 0, stream>>>(Wa, Wa_bf, R_ * E_ / 8);
    k_convert_bf16<<<(D_ * E_ / 8 + 255) / 256, 256, 0, stream>>>(Wc, Wc_bf, D_ * E_ / 8);
    k_convert_bf16<<<(BT_ * E_ / 8 + 255) / 256, 256, 0, stream>>>(enc, enc_bf, BT_ * E_ / 8);

    // 2) gather embedding rows
    k_gather_emb<<<(BT_ * 64) / 256, 256, 0, stream>>>(trg, embW_bf, emb_bf);

    // 3) gx_emb = emb @ W_ih[:, :512]^T + b_ih -> [t][j][b]
    k_gemm_bf16<<<(BT_ / 128) * (G3_ / 128), 256, 0, stream>>>(
        emb_bf, Wih_bf, bih, gxe, BT_, G3_, 512, 512, 1024, 1);

    // 4) enc_proj = enc @ W_a^T; encWc = enc @ W_c^T
    k_gemm_bf16<<<(BT_ / 128) * (R_ / 128), 256, 0, stream>>>(
        enc_bf, Wa_bf, nullptr, encproj, BT_, R_, 512, 512, 512, 0);
    k_gemm_bf16<<<(BT_ / 128) * (D_ / 128), 256, 0, stream>>>(
        enc_bf, Wc_bf, nullptr, encWc, BT_, D_, 512, 512, 512, 0);

    // 5) pack weights / state
    k_pack_gates<<<(G3_ * 1024) / 256, 256, 0, stream>>>(Wih, Whh, Wg);
    k_convert_f16<<<(512 * 512 / 8 + 255) / 256, 256, 0, stream>>>(Wh, whf16, 512 * 512 / 8);
    k_convert_f16<<<(BT_ * 512 / 8 + 255) / 256, 256, 0, stream>>>(encproj, epf16, BT_ * 512 / 8);
    k_pack_ewT<<<(32 * 512 * 64) / 256, 256, 0, stream>>>(encWc, encWcT);
    k_init_state<<<(32 * 1024) / 256, 256, 0, stream>>>(init_h, x16, hbuf);
    (void)hipMemsetAsync(bar, 0, 8, stream);

    // 6) persistent recurrence
    k_recur<<<NWG, 512, 0, stream>>>(Wg, whf16, epf16, encWcT, gxe, bhh, mask, bh, bc,
                                     x16, hbuf, o_bf, bar);

    // 7) logits = o @ emb_W^T + b_logits
    k_gemm_bf16<<<(BT_ / 128) * (V_ / 128), 256, 0, stream>>>(
        o_bf, embW_bf, blog, out, BT_, V_, 512, 512, 512, 0);
}

// Round 10
// 2556.345 us; speedup vs baseline: 2.5495x; 1.0698x over previous
//
#include <hip/hip_runtime.h>

#define V_ 32000
#define D_ 512
#define R_ 512
#define E_ 512
#define B_ 32
#define T_ 64
#define S_ 64
#define BT_ (B_ * T_)   // 2048
#define G3_ (3 * R_)    // 1536
#define NWG 64          // persistent-kernel workgroups

typedef _Float16 f16;
typedef _Float16 f16x2 __attribute__((ext_vector_type(2)));
typedef _Float16 f16x4 __attribute__((ext_vector_type(4)));
typedef _Float16 f16x8 __attribute__((ext_vector_type(8)));
typedef __bf16 bf16x8 __attribute__((ext_vector_type(8)));
typedef float f32x4 __attribute__((ext_vector_type(4)));
typedef unsigned long long ull;

#define PAIR(v, i) (f16x2){(v)[2*(i)], (v)[2*(i)+1]}

__device__ __forceinline__ float fdot2_(f16x2 a, f16x2 b, float c) {
    return __builtin_amdgcn_fdot2(a, b, c, false);
}
__device__ __forceinline__ float sigmoidf_(float x) {
    return 1.0f / (1.0f + __expf(-x));
}

// ---------------- fp32 -> bf16 convert ----------------
__global__ __launch_bounds__(256) void k_convert_bf16(const float* __restrict__ src,
                                                      __bf16* __restrict__ dst, int n8) {
    int i = blockIdx.x * 256 + threadIdx.x;
    if (i >= n8) return;
    float4 a = *(const float4*)&src[(size_t)i * 8];
    float4 b = *(const float4*)&src[(size_t)i * 8 + 4];
    bf16x8 o;
    o[0] = (__bf16)a.x; o[1] = (__bf16)a.y; o[2] = (__bf16)a.z; o[3] = (__bf16)a.w;
    o[4] = (__bf16)b.x; o[5] = (__bf16)b.y; o[6] = (__bf16)b.z; o[7] = (__bf16)b.w;
    *(bf16x8*)&dst[(size_t)i * 8] = o;
}

// ---------------- fp32 -> f16 convert ----------------
__global__ __launch_bounds__(256) void k_convert_f16(const float* __restrict__ src,
                                                     f16* __restrict__ dst, int n8) {
    int i = blockIdx.x * 256 + threadIdx.x;
    if (i >= n8) return;
    float4 a = *(const float4*)&src[(size_t)i * 8];
    float4 b = *(const float4*)&src[(size_t)i * 8 + 4];
    f16x8 o;
    o[0] = (f16)a.x; o[1] = (f16)a.y; o[2] = (f16)a.z; o[3] = (f16)a.w;
    o[4] = (f16)b.x; o[5] = (f16)b.y; o[6] = (f16)b.z; o[7] = (f16)b.w;
    *(f16x8*)&dst[(size_t)i * 8] = o;
}

// ---------------- gather embedding rows (bf16) ----------------
__global__ __launch_bounds__(256) void k_gather_emb(const int* __restrict__ trg,
                                                    const __bf16* __restrict__ embW,
                                                    __bf16* __restrict__ dst) {
    int id = blockIdx.x * 256 + threadIdx.x;
    int bt = id >> 6, c = id & 63;
    int tok = trg[bt];
    *(uint4*)&dst[(size_t)bt * 512 + c * 8] = *(const uint4*)&embW[(size_t)tok * 512 + c * 8];
}

// ---------------- bf16 MFMA GEMM: C = A[M,K] * B^T[N,K] (+bias) ----------------
__global__ __launch_bounds__(256) void k_gemm_bf16(const __bf16* __restrict__ A,
                                                   const __bf16* __restrict__ B,
                                                   const float* __restrict__ bias,
                                                   float* __restrict__ out,
                                                   int M, int N, int K, int lda, int ldb,
                                                   int mode) {
    __shared__ __bf16 lA[128 * 40];
    __shared__ __bf16 lB[128 * 40];
    const int Mt = M >> 7;
    const int mt = blockIdx.x % Mt, nt = blockIdx.x / Mt;
    const int m0 = mt << 7, n0 = nt << 7;
    const int tid = threadIdx.x;
    const int w = tid >> 6, ln = tid & 63;
    const int wm = w >> 1, wn = w & 1;

    f32x4 acc[4][4];
#pragma unroll
    for (int mi = 0; mi < 4; ++mi)
#pragma unroll
        for (int ni = 0; ni < 4; ++ni) acc[mi][ni] = (f32x4){0.f, 0.f, 0.f, 0.f};

    const int k0 = (ln >> 4) * 8, rr = ln & 15;

    for (int kk = 0; kk < K; kk += 32) {
        __syncthreads();
#pragma unroll
        for (int p = 0; p < 2; ++p) {
            int i = p * 256 + tid;
            int r = i >> 2, q = i & 3;
            *(uint4*)&lA[r * 40 + q * 8] = *(const uint4*)&A[(size_t)(m0 + r) * lda + kk + q * 8];
            *(uint4*)&lB[r * 40 + q * 8] = *(const uint4*)&B[(size_t)(n0 + r) * ldb + kk + q * 8];
        }
        __syncthreads();
        bf16x8 af[4], bf[4];
#pragma unroll
        for (int mi = 0; mi < 4; ++mi) af[mi] = *(bf16x8*)&lA[(wm * 64 + mi * 16 + rr) * 40 + k0];
#pragma unroll
        for (int ni = 0; ni < 4; ++ni) bf[ni] = *(bf16x8*)&lB[(wn * 64 + ni * 16 + rr) * 40 + k0];
#pragma unroll
        for (int mi = 0; mi < 4; ++mi)
#pragma unroll
            for (int ni = 0; ni < 4; ++ni)
                acc[mi][ni] = __builtin_amdgcn_mfma_f32_16x16x32_bf16(af[mi], bf[ni], acc[mi][ni], 0, 0, 0);
    }

    const int rq = ln >> 4;
#pragma unroll
    for (int mi = 0; mi < 4; ++mi) {
#pragma unroll
        for (int ni = 0; ni < 4; ++ni) {
            int col = n0 + wn * 64 + ni * 16 + rr;
            float bv = bias ? bias[col] : 0.f;
#pragma unroll
            for (int reg = 0; reg < 4; ++reg) {
                int row = m0 + wm * 64 + mi * 16 + rq * 4 + reg;
                float v = acc[mi][ni][reg] + bv;
                if (mode == 0) {
                    out[(size_t)row * N + col] = v;
                } else {
                    int bb = row >> 6, tt = row & 63;
                    out[((size_t)tt * G3_ + col) * B_ + bb] = v;
                }
            }
        }
    }
}

// ---------------- weight packing (one-time) ----------------
__global__ __launch_bounds__(256) void k_pack_gates(const float* __restrict__ Wih,
                                                    const float* __restrict__ Whh,
                                                    f16* __restrict__ Wg) {
    int idx = blockIdx.x * 256 + threadIdx.x;  // 1536*1024
    int j3 = idx >> 10, k = idx & 1023;
    float v = (k < 512) ? Wih[(size_t)j3 * 1024 + 512 + k] : Whh[(size_t)j3 * 512 + (k - 512)];
    Wg[idx] = (f16)v;
}
__global__ __launch_bounds__(256) void k_pack_ewT(const float* __restrict__ ew, f16* __restrict__ ewT) {
    int idx = blockIdx.x * 256 + threadIdx.x;  // 32*512*64
    int b = idx >> 15, d = (idx >> 6) & 511, s = idx & 63;
    ewT[idx] = (f16)ew[((size_t)b * 64 + s) * 512 + d];
}
// x16[0] = [o=0(0..511) | h=init_h(512..1023)] f16 per b; hbuf[0] = init_h f32
__global__ __launch_bounds__(256) void k_init_state(const float* __restrict__ init_h,
                                                    f16* __restrict__ x16,
                                                    float* __restrict__ hbuf) {
    int idx = blockIdx.x * 256 + threadIdx.x;  // 32*1024
    int b = idx >> 10, k = idx & 1023;
    if (k < 512) {
        x16[idx] = (f16)0.f;
    } else {
        float v = init_h[(size_t)b * 512 + (k - 512)];
        x16[idx] = (f16)v;
        hbuf[(size_t)b * 512 + (k - 512)] = v;
    }
}

// ---------------- flag barrier: per-wg arrive slots + single go line ----------------
// Arrivals: plain sc0 sc1 store of epoch to a private 128B-spaced slot (no RMW).
// Detection: wg0's first wave polls all 64 slots with ONE 64-lane load + __all,
// then stores epoch to `go`. Other wgs poll only `go` (read-only line, 1 writer).
__device__ __forceinline__ void flagbar(unsigned* arrive, unsigned* go, unsigned ep,
                                        int wgid, int tid) {
    asm volatile("s_waitcnt vmcnt(0)" ::: "memory");
    __syncthreads();
    if (wgid == 0) {
        if (tid < 64) {
            if (tid == 0) {
                uint64_t a = (uint64_t)arrive;
                asm volatile("global_store_dword %0, %1, off sc0 sc1" :: "v"(a), "v"(ep) : "memory");
            }
            uint64_t a = (uint64_t)(arrive + (size_t)tid * 32);
            while (true) {
                unsigned v;
                asm volatile("global_load_dword %0, %1, off sc0 sc1\n\ts_waitcnt vmcnt(0)"
                             : "=&v"(v) : "v"(a) : "memory");
                if (__all(v >= ep)) break;
                __builtin_amdgcn_s_sleep(2);
            }
            if (tid == 0) {
                uint64_t g = (uint64_t)go;
                asm volatile("global_store_dword %0, %1, off sc0 sc1" :: "v"(g), "v"(ep) : "memory");
            }
        }
    } else {
        if (tid == 0) {
            uint64_t a = (uint64_t)(arrive + (size_t)wgid * 32);
            asm volatile("global_store_dword %0, %1, off sc0 sc1" :: "v"(a), "v"(ep) : "memory");
            uint64_t g = (uint64_t)go;
            while (true) {
                unsigned v;
                asm volatile("global_load_dword %0, %1, off sc0 sc1\n\ts_waitcnt vmcnt(0)"
                             : "=&v"(v) : "v"(g) : "memory");
                if (v >= ep) break;
                __builtin_amdgcn_s_sleep(8);
            }
        }
    }
    __syncthreads();
}

// ---------------- persistent recurrence ----------------
// Identical to R9 except the barrier mechanism (flagbar).
__global__ __launch_bounds__(512, 2) void k_recur(
    const f16* __restrict__ Wg, const f16* __restrict__ whf16,
    const f16* __restrict__ epf16, const f16* __restrict__ encWcT,
    const float* __restrict__ gxe, const float* __restrict__ bhh,
    const float* __restrict__ mask, const float* __restrict__ bh, const float* __restrict__ bc,
    f16* x16, float* __restrict__ hbuf,
    __bf16* __restrict__ obf, unsigned* arrive, unsigned* go) {
    __shared__ __align__(16) f16 x2l[32 * 1032];
    __shared__ __align__(16) f16 hl16[512];
    __shared__ float sc[64];
    __shared__ float s_af[64];
    __shared__ f16x2 a2l[32];

    const int tid = threadIdx.x;
    const int wgid = blockIdx.x;
    const int bA = tid & 31;
    const int half = (tid >> 5) & 1;
    const int jl = tid >> 6;
    const int j = wgid * 8 + jl;

    for (int t = 0; t < T_; ++t) {
        const int cur = t & 1, nxt = cur ^ 1;
        const f16* x2c = x16 + (size_t)cur * 32 * 1024;
        f16* x2n = x16 + (size_t)nxt * 32 * 1024;
        const float* hsrc = hbuf + (size_t)cur * 32 * 512;
        float* hdst = hbuf + (size_t)nxt * 32 * 512;
        const float* gp = gxe + (size_t)t * G3_ * B_;

        // ---- stage x16[cur] (64KB) into LDS: 8 batched coherent 16B loads/thread ----
        {
            uint64_t ab = (uint64_t)(const void*)x2c + (uint64_t)tid * 16;
            uint4 r0, r1, r2, r3, r4, r5, r6, r7;
            asm volatile(
                "global_load_dwordx4 %0, %8, off sc0 sc1\n\t"
                "global_load_dwordx4 %1, %9, off sc0 sc1\n\t"
                "global_load_dwordx4 %2, %10, off sc0 sc1\n\t"
                "global_load_dwordx4 %3, %11, off sc0 sc1\n\t"
                "global_load_dwordx4 %4, %12, off sc0 sc1\n\t"
                "global_load_dwordx4 %5, %13, off sc0 sc1\n\t"
                "global_load_dwordx4 %6, %14, off sc0 sc1\n\t"
                "global_load_dwordx4 %7, %15, off sc0 sc1\n\t"
                "s_waitcnt vmcnt(0)"
                : "=&v"(r0), "=&v"(r1), "=&v"(r2), "=&v"(r3),
                  "=&v"(r4), "=&v"(r5), "=&v"(r6), "=&v"(r7)
                : "v"(ab), "v"(ab + 8192), "v"(ab + 16384), "v"(ab + 24576),
                  "v"(ab + 32768), "v"(ab + 40960), "v"(ab + 49152), "v"(ab + 57344)
                : "memory");
#define STORE_CHUNK(i, r) { int f = tid + (i) * 512; int row = f >> 7, col = f & 127; \
                            *(uint4*)(x2l + row * 1032 + col * 8) = (r); }
            STORE_CHUNK(0, r0) STORE_CHUNK(1, r1) STORE_CHUNK(2, r2) STORE_CHUNK(3, r3)
            STORE_CHUNK(4, r4) STORE_CHUNK(5, r5) STORE_CHUNK(6, r6) STORE_CHUNK(7, r7)
#undef STORE_CHUNK
        }
        __syncthreads();

        // ---- A1: gates + h_new ----
        {
            const f16* xb = x2l + bA * 1032 + half * 512;
            const f16* wr = Wg + (size_t)(j) * 1024 + half * 512;
            const f16* wz = Wg + (size_t)(512 + j) * 1024 + half * 512;
            const f16* wn = Wg + (size_t)(1024 + j) * 1024 + half * 512;
            float ar = 0.f, az = 0.f, an = 0.f;
#pragma unroll 4
            for (int c = 0; c < 64; ++c) {
                f16x8 xv = *(const f16x8*)(xb + c * 8);
                f16x8 wrv = *(const f16x8*)(wr + c * 8);
                f16x8 wzv = *(const f16x8*)(wz + c * 8);
                f16x8 wnv = *(const f16x8*)(wn + c * 8);
#pragma unroll
                for (int q = 0; q < 4; ++q) {
                    f16x2 xp = PAIR(xv, q);
                    ar = fdot2_(xp, PAIR(wrv, q), ar);
                    az = fdot2_(xp, PAIR(wzv, q), az);
                    an = fdot2_(xp, PAIR(wnv, q), an);
                }
            }
            float aro = __shfl_xor(ar, 32);
            float azo = __shfl_xor(az, 32);
            float ano = __shfl_xor(an, 32);
            float gr = gp[(size_t)j * 32 + bA];
            float gz = gp[(size_t)(512 + j) * 32 + bA];
            float gn = gp[(size_t)(1024 + j) * 32 + bA];
            float rpre = gr + bhh[j] + ar + aro;
            float zpre = gz + bhh[512 + j] + az + azo;
            float r = sigmoidf_(rpre);
            float z = sigmoidf_(zpre);
            float gxn = gn + (half ? ano : an);
            float ghn = bhh[1024 + j] + (half ? an : ano);
            float n = tanhf(gxn + r * ghn);
            float hp = hsrc[(size_t)bA * 512 + j];
            float hnew = (1.f - z) * n + z * hp;
            if (half == 0) {
                hdst[(size_t)bA * 512 + j] = hnew;         // own-wg f32 copy (cached)
                f16 h16 = (f16)hnew;
                unsigned short us; __builtin_memcpy(&us, &h16, 2);
                unsigned hv = us;
                uint64_t a = (uint64_t)(void*)x2n + (uint64_t)(bA * 2048 + 1024 + j * 2);
                asm volatile("global_store_short %0, %1, off sc0 sc1" :: "v"(a), "v"(hv) : "memory");
            }
        }

        flagbar(arrive, go, (unsigned)(2 * t + 1), wgid, tid);

        // ---- Phase B (wg = b): scores + softmax + output ----
        if (wgid < 32) {
            const int b = wgid;
            if (tid < 64) {
                uint64_t a = (uint64_t)(void*)x2n + (uint64_t)(b * 2048 + 1024) + (uint64_t)tid * 16;
                uint4 r;
                asm volatile("global_load_dwordx4 %0, %1, off sc0 sc1\n\t"
                             "s_waitcnt vmcnt(0)"
                             : "=&v"(r) : "v"(a) : "memory");
                *(uint4*)(hl16 + tid * 8) = r;
            }
            __syncthreads();
            // scores: s = tid>>3, q = tid&7
            {
                int s = tid >> 3, q = tid & 7;
                const f16* ep = epf16 + ((size_t)(b * 64 + s)) * 512 + q * 64;
                const f16* hh = hl16 + q * 64;
                float a = 0.f;
#pragma unroll
                for (int c = 0; c < 8; ++c) {
                    f16x8 ev = *(const f16x8*)(ep + c * 8);
                    f16x8 xv = *(const f16x8*)(hh + c * 8);
#pragma unroll
                    for (int qq = 0; qq < 4; ++qq) a = fdot2_(PAIR(ev, qq), PAIR(xv, qq), a);
                }
                a += __shfl_xor(a, 1);
                a += __shfl_xor(a, 2);
                a += __shfl_xor(a, 4);
                if (q == 0) sc[s] = a;
            }
            __syncthreads();
            if (tid < 64) {
                float s = sc[tid];
                s = (mask[b * 64 + tid] > 0.f) ? s : -1e9f;
                float m = s;
#pragma unroll
                for (int d = 1; d < 64; d <<= 1) m = fmaxf(m, __shfl_xor(m, d));
                float e = __expf(s - m);
                float sum = e;
#pragma unroll
                for (int d = 1; d < 64; d <<= 1) sum += __shfl_xor(sum, d);
                s_af[tid] = e / sum;
            }
            __syncthreads();
            if (tid < 32) {
                a2l[tid] = (f16x2){(f16)s_af[2 * tid], (f16)s_af[2 * tid + 1]};
            }
            __syncthreads();
            // u = b_h + b_c + Wh[d]·h + sum_s a_s encWc[b][s][d];  d = tid
            {
                const int d = tid;
                float u = bh[d] + bc[d];
                const f16* wrow = whf16 + (size_t)d * 512;
#pragma unroll 8
                for (int c = 0; c < 64; ++c) {
                    f16x8 wv = *(const f16x8*)(wrow + c * 8);
                    f16x8 xv = *(const f16x8*)(hl16 + c * 8);
#pragma unroll
                    for (int qq = 0; qq < 4; ++qq) u = fdot2_(PAIR(wv, qq), PAIR(xv, qq), u);
                }
                const f16* ew = encWcT + ((size_t)b * 512 + d) * 64;
#pragma unroll
                for (int c = 0; c < 8; ++c) {
                    f16x8 ev = *(const f16x8*)(ew + c * 8);
#pragma unroll
                    for (int qq = 0; qq < 4; ++qq) u = fdot2_(PAIR(ev, qq), a2l[c * 4 + qq], u);
                }
                float o = tanhf(u);
                obf[((size_t)b * 64 + t) * 512 + d] = (__bf16)o;
                float o2 = __shfl_xor(o, 1);
                if ((tid & 1) == 0) {
                    f16x2 pv = {(f16)o, (f16)o2};
                    unsigned uv; __builtin_memcpy(&uv, &pv, 4);
                    uint64_t a = (uint64_t)(void*)x2n + (uint64_t)(b * 2048 + d * 2);
                    asm volatile("global_store_dword %0, %1, off sc0 sc1" :: "v"(a), "v"(uv) : "memory");
                }
            }
        }

        flagbar(arrive, go, (unsigned)(2 * t + 2), wgid, tid);
    }
}

extern "C" void kernel_launch(void* const* d_in, const int* in_sizes, int n_in,
                              void* d_out, int out_size, void* d_ws, size_t ws_size,
                              hipStream_t stream) {
    const int* trg = (const int*)d_in[0];
    const float* enc = (const float*)d_in[1];
    const float* init_h = (const float*)d_in[2];
    const float* mask = (const float*)d_in[3];
    const float* embW = (const float*)d_in[4];
    const float* Wih = (const float*)d_in[5];
    const float* Whh = (const float*)d_in[6];
    const float* bih = (const float*)d_in[7];
    const float* bhh = (const float*)d_in[8];
    const float* Wa = (const float*)d_in[9];
    const float* Wh = (const float*)d_in[10];
    const float* bh = (const float*)d_in[11];
    const float* Wc = (const float*)d_in[12];
    const float* bc = (const float*)d_in[13];
    const float* blog = (const float*)d_in[14];
    float* out = (float*)d_out;

    char* w = (char*)d_ws;
    auto alloc = [&](size_t bytes) { char* p = w; w += (bytes + 255) & ~(size_t)255; return p; };
    __bf16* embW_bf = (__bf16*)alloc((size_t)V_ * D_ * 2);
    __bf16* Wih_bf  = (__bf16*)alloc((size_t)G3_ * 1024 * 2);
    __bf16* Wa_bf   = (__bf16*)alloc((size_t)R_ * E_ * 2);
    __bf16* Wc_bf   = (__bf16*)alloc((size_t)D_ * E_ * 2);
    __bf16* enc_bf  = (__bf16*)alloc((size_t)BT_ * E_ * 2);
    __bf16* emb_bf  = (__bf16*)alloc((size_t)BT_ * D_ * 2);
    float* gxe      = (float*)alloc((size_t)T_ * G3_ * B_ * 4);
    float* encproj  = (float*)alloc((size_t)BT_ * R_ * 4);
    float* encWc    = (float*)alloc((size_t)BT_ * D_ * 4);
    f16* Wg         = (f16*)alloc((size_t)G3_ * 1024 * 2);
    f16* whf16      = (f16*)alloc((size_t)512 * 512 * 2);
    f16* epf16      = (f16*)alloc((size_t)BT_ * 512 * 2);
    f16* encWcT     = (f16*)alloc((size_t)32 * 512 * 64 * 2);
    f16* x16        = (f16*)alloc((size_t)2 * 32 * 1024 * 2);
    float* hbuf     = (float*)alloc((size_t)2 * 32 * 512 * 4);
    __bf16* o_bf    = (__bf16*)alloc((size_t)BT_ * D_ * 2);
    unsigned* sync_ = (unsigned*)alloc(16384);   // arrive[64 slots x 128B] + go
    unsigned* arrive = sync_;
    unsigned* go     = sync_ + 64 * 32;

    // 1) converts
    k_convert_bf16<<<(V_ * D_ / 8 + 255) / 256, 256, 0, stream>>>(embW, embW_bf, V_ * D_ / 8);
    k_convert_bf16<<<(G3_ * 1024 / 8 + 255) / 256, 256, 0, stream>>>(Wih, Wih_bf, G3_ * 1024 / 8);
    k_convert_bf16<<<(R_ * E_ / 8 + 255) / 256, 256, 0, stream>>>(Wa, Wa_bf, R_ * E_ / 8);
    k_convert_bf16<<<(D_ * E_ / 8 + 255) / 256, 256, 0, stream>>>(Wc, Wc_bf, D_ * E_ / 8);
    k_convert_bf16<<<(BT_ * E_ / 8 + 255) / 256, 256, 0, stream>>>(enc, enc_bf, BT_ * E_ / 8);

    // 2) gather embedding rows
    k_gather_emb<<<(BT_ * 64) / 256, 256, 0, stream>>>(trg, embW_bf, emb_bf);

    // 3) gx_emb = emb @ W_ih[:, :512]^T + b_ih -> [t][j][b]
    k_gemm_bf16<<<(BT_ / 128) * (G3_ / 128), 256, 0, stream>>>(
        emb_bf, Wih_bf, bih, gxe, BT_, G3_, 512, 512, 1024, 1);

    // 4) enc_proj = enc @ W_a^T; encWc = enc @ W_c^T
    k_gemm_bf16<<<(BT_ / 128) * (R_ / 128), 256, 0, stream>>>(
        enc_bf, Wa_bf, nullptr, encproj, BT_, R_, 512, 512, 512, 0);
    k_gemm_bf16<<<(BT_ / 128) * (D_ / 128), 256, 0, stream>>>(
        enc_bf, Wc_bf, nullptr, encWc, BT_, D_, 512, 512, 512, 0);

    // 5) pack weights / state
    k_pack_gates<<<(G3_ * 1024) / 256, 256, 0, stream>>>(Wih, Whh, Wg);
    k_convert_f16<<<(512 * 512 / 8 + 255) / 256, 256, 0, stream>>>(Wh, whf16, 512 * 512 / 8);
    k_convert_f16<<<(BT_ * 512 / 8 + 255) / 256, 256, 0, stream>>>(encproj, epf16, BT_ * 512 / 8);
    k_pack_ewT<<<(32 * 512 * 64) / 256, 256, 0, stream>>>(encWc, encWcT);
    k_init_state<<<(32 * 1024) / 256, 256, 0, stream>>>(init_h, x16, hbuf);
    (void)hipMemsetAsync(sync_, 0, 16384, stream);

    // 6) persistent recurrence
    k_recur<<<NWG, 512, 0, stream>>>(Wg, whf16, epf16, encWcT, gxe, bhh, mask, bh, bc,
                                     x16, hbuf, o_bf, arrive, go);

    // 7) logits = o @ emb_W^T + b_logits
    k_gemm_bf16<<<(BT_ / 128) * (V_ / 128), 256, 0, stream>>>(
        o_bf, embW_bf, blog, out, BT_, V_, 512, 512, 512, 0);
}

// Round 12
// 1613.005 us; speedup vs baseline: 4.0405x; 1.5848x over previous
//
#include <hip/hip_runtime.h>

#define V_ 32000
#define D_ 512
#define R_ 512
#define E_ 512
#define B_ 32
#define T_ 64
#define S_ 64
#define BT_ (B_ * T_)   // 2048
#define G3_ (3 * R_)    // 1536

typedef _Float16 f16;
typedef _Float16 f16x2 __attribute__((ext_vector_type(2)));
typedef _Float16 f16x8 __attribute__((ext_vector_type(8)));
typedef __bf16 bf16x8 __attribute__((ext_vector_type(8)));
typedef float f32x4 __attribute__((ext_vector_type(4)));

#define PAIR(v, i) (f16x2){(v)[2*(i)], (v)[2*(i)+1]}

__device__ __forceinline__ float fdot2_(f16x2 a, f16x2 b, float c) {
    return __builtin_amdgcn_fdot2(a, b, c, false);
}
__device__ __forceinline__ float sigmoidf_(float x) {
    return 1.0f / (1.0f + __expf(-x));
}

// ---------------- fp32 -> bf16 convert ----------------
__global__ __launch_bounds__(256) void k_convert_bf16(const float* __restrict__ src,
                                                      __bf16* __restrict__ dst, int n8) {
    int i = blockIdx.x * 256 + threadIdx.x;
    if (i >= n8) return;
    float4 a = *(const float4*)&src[(size_t)i * 8];
    float4 b = *(const float4*)&src[(size_t)i * 8 + 4];
    bf16x8 o;
    o[0] = (__bf16)a.x; o[1] = (__bf16)a.y; o[2] = (__bf16)a.z; o[3] = (__bf16)a.w;
    o[4] = (__bf16)b.x; o[5] = (__bf16)b.y; o[6] = (__bf16)b.z; o[7] = (__bf16)b.w;
    *(bf16x8*)&dst[(size_t)i * 8] = o;
}

// ---------------- fp32 -> f16 convert ----------------
__global__ __launch_bounds__(256) void k_convert_f16(const float* __restrict__ src,
                                                     f16* __restrict__ dst, int n8) {
    int i = blockIdx.x * 256 + threadIdx.x;
    if (i >= n8) return;
    float4 a = *(const float4*)&src[(size_t)i * 8];
    float4 b = *(const float4*)&src[(size_t)i * 8 + 4];
    f16x8 o;
    o[0] = (f16)a.x; o[1] = (f16)a.y; o[2] = (f16)a.z; o[3] = (f16)a.w;
    o[4] = (f16)b.x; o[5] = (f16)b.y; o[6] = (f16)b.z; o[7] = (f16)b.w;
    *(f16x8*)&dst[(size_t)i * 8] = o;
}

// ---------------- gather embedding rows (bf16) ----------------
__global__ __launch_bounds__(256) void k_gather_emb(const int* __restrict__ trg,
                                                    const __bf16* __restrict__ embW,
                                                    __bf16* __restrict__ dst) {
    int id = blockIdx.x * 256 + threadIdx.x;
    int bt = id >> 6, c = id & 63;
    int tok = trg[bt];
    *(uint4*)&dst[(size_t)bt * 512 + c * 8] = *(const uint4*)&embW[(size_t)tok * 512 + c * 8];
}

// ---------------- bf16 MFMA GEMM: C = A[M,K] * B^T[N,K] (+bias) ----------------
__global__ __launch_bounds__(256) void k_gemm_bf16(const __bf16* __restrict__ A,
                                                   const __bf16* __restrict__ B,
                                                   const float* __restrict__ bias,
                                                   float* __restrict__ out,
                                                   int M, int N, int K, int lda, int ldb,
                                                   int mode) {
    __shared__ __bf16 lA[128 * 40];
    __shared__ __bf16 lB[128 * 40];
    const int Mt = M >> 7;
    const int mt = blockIdx.x % Mt, nt = blockIdx.x / Mt;
    const int m0 = mt << 7, n0 = nt << 7;
    const int tid = threadIdx.x;
    const int w = tid >> 6, ln = tid & 63;
    const int wm = w >> 1, wn = w & 1;

    f32x4 acc[4][4];
#pragma unroll
    for (int mi = 0; mi < 4; ++mi)
#pragma unroll
        for (int ni = 0; ni < 4; ++ni) acc[mi][ni] = (f32x4){0.f, 0.f, 0.f, 0.f};

    const int k0 = (ln >> 4) * 8, rr = ln & 15;

    for (int kk = 0; kk < K; kk += 32) {
        __syncthreads();
#pragma unroll
        for (int p = 0; p < 2; ++p) {
            int i = p * 256 + tid;
            int r = i >> 2, q = i & 3;
            *(uint4*)&lA[r * 40 + q * 8] = *(const uint4*)&A[(size_t)(m0 + r) * lda + kk + q * 8];
            *(uint4*)&lB[r * 40 + q * 8] = *(const uint4*)&B[(size_t)(n0 + r) * ldb + kk + q * 8];
        }
        __syncthreads();
        bf16x8 af[4], bf[4];
#pragma unroll
        for (int mi = 0; mi < 4; ++mi) af[mi] = *(bf16x8*)&lA[(wm * 64 + mi * 16 + rr) * 40 + k0];
#pragma unroll
        for (int ni = 0; ni < 4; ++ni) bf[ni] = *(bf16x8*)&lB[(wn * 64 + ni * 16 + rr) * 40 + k0];
#pragma unroll
        for (int mi = 0; mi < 4; ++mi)
#pragma unroll
            for (int ni = 0; ni < 4; ++ni)
                acc[mi][ni] = __builtin_amdgcn_mfma_f32_16x16x32_bf16(af[mi], bf[ni], acc[mi][ni], 0, 0, 0);
    }

    const int rq = ln >> 4;
#pragma unroll
    for (int mi = 0; mi < 4; ++mi) {
#pragma unroll
        for (int ni = 0; ni < 4; ++ni) {
            int col = n0 + wn * 64 + ni * 16 + rr;
            float bv = bias ? bias[col] : 0.f;
#pragma unroll
            for (int reg = 0; reg < 4; ++reg) {
                int row = m0 + wm * 64 + mi * 16 + rq * 4 + reg;
                float v = acc[mi][ni][reg] + bv;
                if (mode == 0) {
                    out[(size_t)row * N + col] = v;
                } else {
                    int bb = row >> 6, tt = row & 63;
                    out[((size_t)tt * G3_ + col) * B_ + bb] = v;
                }
            }
        }
    }
}

// ---------------- weight packing (one-time) ----------------
__global__ __launch_bounds__(256) void k_pack_gates(const float* __restrict__ Wih,
                                                    const float* __restrict__ Whh,
                                                    f16* __restrict__ Wg) {
    int idx = blockIdx.x * 256 + threadIdx.x;  // 1536*1024
    int j3 = idx >> 10, k = idx & 1023;
    float v = (k < 512) ? Wih[(size_t)j3 * 1024 + 512 + k] : Whh[(size_t)j3 * 512 + (k - 512)];
    Wg[idx] = (f16)v;
}
__global__ __launch_bounds__(256) void k_pack_ewT(const float* __restrict__ ew, f16* __restrict__ ewT) {
    int idx = blockIdx.x * 256 + threadIdx.x;  // 32*512*64
    int b = idx >> 15, d = (idx >> 6) & 511, s = idx & 63;
    ewT[idx] = (f16)ew[((size_t)b * 64 + s) * 512 + d];
}
// x16[0] = [o=0(0..511) | h=init_h(512..1023)] f16 per b; hbuf[0] = init_h f32
__global__ __launch_bounds__(256) void k_init_state(const float* __restrict__ init_h,
                                                    f16* __restrict__ x16,
                                                    float* __restrict__ hbuf) {
    int idx = blockIdx.x * 256 + threadIdx.x;  // 32*1024
    int b = idx >> 10, k = idx & 1023;
    if (k < 512) {
        x16[idx] = (f16)0.f;
    } else {
        float v = init_h[(size_t)b * 512 + (k - 512)];
        x16[idx] = (f16)v;
        hbuf[(size_t)b * 512 + (k - 512)] = v;
    }
}

// ---------------- stepA: GRU gates + h_new (one launch per t) ----------------
// 128 wgs x 256 thr; wg owns 4 j. thread = (jl[4], half[2], b[32]).
__global__ __launch_bounds__(256) void k_stepA(
    const f16* __restrict__ Wg, const float* __restrict__ gp, const float* __restrict__ bhh,
    const f16* __restrict__ x_in, f16* __restrict__ x_out,
    const float* __restrict__ h_in, float* __restrict__ h_out) {
    __shared__ __align__(16) f16 x2l[32 * 1032];
    const int tid = threadIdx.x;
    const int wgid = blockIdx.x;
    const int bA = tid & 31;
    const int half = (tid >> 5) & 1;
    const int jl = tid >> 6;           // 0..3
    const int j = wgid * 4 + jl;

    // stage x_in (64KB = 4096 uint4) into LDS rows of 1032 f16
#pragma unroll
    for (int i = 0; i < 16; ++i) {
        int f = tid + i * 256;
        int row = f >> 7, col = f & 127;
        *(uint4*)(x2l + row * 1032 + col * 8) = *(const uint4*)(x_in + (size_t)f * 8);
    }
    __syncthreads();

    const f16* xb = x2l + bA * 1032 + half * 512;
    const f16* wr = Wg + (size_t)(j) * 1024 + half * 512;
    const f16* wz = Wg + (size_t)(512 + j) * 1024 + half * 512;
    const f16* wn = Wg + (size_t)(1024 + j) * 1024 + half * 512;
    float ar = 0.f, az = 0.f, an = 0.f;
#pragma unroll 4
    for (int c = 0; c < 64; ++c) {
        f16x8 xv = *(const f16x8*)(xb + c * 8);
        f16x8 wrv = *(const f16x8*)(wr + c * 8);
        f16x8 wzv = *(const f16x8*)(wz + c * 8);
        f16x8 wnv = *(const f16x8*)(wn + c * 8);
#pragma unroll
        for (int q = 0; q < 4; ++q) {
            f16x2 xp = PAIR(xv, q);
            ar = fdot2_(xp, PAIR(wrv, q), ar);
            az = fdot2_(xp, PAIR(wzv, q), az);
            an = fdot2_(xp, PAIR(wnv, q), an);
        }
    }
    float aro = __shfl_xor(ar, 32);
    float azo = __shfl_xor(az, 32);
    float ano = __shfl_xor(an, 32);
    float gr = gp[(size_t)j * 32 + bA];
    float gz = gp[(size_t)(512 + j) * 32 + bA];
    float gn = gp[(size_t)(1024 + j) * 32 + bA];
    float rpre = gr + bhh[j] + ar + aro;
    float zpre = gz + bhh[512 + j] + az + azo;
    float r = sigmoidf_(rpre);
    float z = sigmoidf_(zpre);
    float gxn = gn + (half ? ano : an);
    float ghn = bhh[1024 + j] + (half ? an : ano);
    float n = tanhf(gxn + r * ghn);
    float hp = h_in[(size_t)bA * 512 + j];
    float hnew = (1.f - z) * n + z * hp;
    if (half == 0) {
        h_out[(size_t)bA * 512 + j] = hnew;
        x_out[(size_t)bA * 1024 + 512 + j] = (f16)hnew;
    }
}

// ---------------- stepB: attention + output (one launch per t) ----------------
// 64 wgs x 256 thr; wg = (b, d-half). Scores/softmax computed per wg (cheap).
__global__ __launch_bounds__(256) void k_stepB(
    const f16* __restrict__ whf16, const f16* __restrict__ epf16, const f16* __restrict__ encWcT,
    const float* __restrict__ mask, const float* __restrict__ bh, const float* __restrict__ bc,
    f16* __restrict__ x_out, __bf16* __restrict__ obf, int t) {
    __shared__ __align__(16) f16 hl16[512];
    __shared__ float sc_[64];
    __shared__ float s_af[64];
    __shared__ f16x2 a2l[32];
    const int tid = threadIdx.x;
    const int b = blockIdx.x >> 1, dh = blockIdx.x & 1;

    if (tid < 64) {
        *(uint4*)(hl16 + tid * 8) = *(const uint4*)(x_out + (size_t)b * 1024 + 512 + tid * 8);
    }
    __syncthreads();

    // scores: s = tid>>2 (0..63), q = tid&3 (128 f16 chunk each)
    {
        int s = tid >> 2, q = tid & 3;
        const f16* ep = epf16 + ((size_t)(b * 64 + s)) * 512 + q * 128;
        const f16* hh = hl16 + q * 128;
        float a = 0.f;
#pragma unroll
        for (int c = 0; c < 16; ++c) {
            f16x8 ev = *(const f16x8*)(ep + c * 8);
            f16x8 xv = *(const f16x8*)(hh + c * 8);
#pragma unroll
            for (int qq = 0; qq < 4; ++qq) a = fdot2_(PAIR(ev, qq), PAIR(xv, qq), a);
        }
        a += __shfl_xor(a, 1);
        a += __shfl_xor(a, 2);
        if (q == 0) sc_[s] = a;
    }
    __syncthreads();
    if (tid < 64) {
        float s = sc_[tid];
        s = (mask[b * 64 + tid] > 0.f) ? s : -1e9f;
        float m = s;
#pragma unroll
        for (int d = 1; d < 64; d <<= 1) m = fmaxf(m, __shfl_xor(m, d));
        float e = __expf(s - m);
        float sum = e;
#pragma unroll
        for (int d = 1; d < 64; d <<= 1) sum += __shfl_xor(sum, d);
        s_af[tid] = e / sum;
    }
    __syncthreads();
    if (tid < 32) {
        a2l[tid] = (f16x2){(f16)s_af[2 * tid], (f16)s_af[2 * tid + 1]};
    }
    __syncthreads();
    // u = b_h + b_c + Wh[d]·h + sum_s a_s encWc[b][s][d];  d = dh*256 + tid
    {
        const int d = dh * 256 + tid;
        float u = bh[d] + bc[d];
        const f16* wrow = whf16 + (size_t)d * 512;
#pragma unroll 8
        for (int c = 0; c < 64; ++c) {
            f16x8 wv = *(const f16x8*)(wrow + c * 8);
            f16x8 xv = *(const f16x8*)(hl16 + c * 8);
#pragma unroll
            for (int qq = 0; qq < 4; ++qq) u = fdot2_(PAIR(wv, qq), PAIR(xv, qq), u);
        }
        const f16* ew = encWcT + ((size_t)b * 512 + d) * 64;
#pragma unroll
        for (int c = 0; c < 8; ++c) {
            f16x8 ev = *(const f16x8*)(ew + c * 8);
#pragma unroll
            for (int qq = 0; qq < 4; ++qq) u = fdot2_(PAIR(ev, qq), a2l[c * 4 + qq], u);
        }
        float o = tanhf(u);
        obf[((size_t)b * 64 + t) * 512 + d] = (__bf16)o;
        x_out[(size_t)b * 1024 + d] = (f16)o;
    }
}

extern "C" void kernel_launch(void* const* d_in, const int* in_sizes, int n_in,
                              void* d_out, int out_size, void* d_ws, size_t ws_size,
                              hipStream_t stream) {
    const int* trg = (const int*)d_in[0];
    const float* enc = (const float*)d_in[1];
    const float* init_h = (const float*)d_in[2];
    const float* mask = (const float*)d_in[3];
    const float* embW = (const float*)d_in[4];
    const float* Wih = (const float*)d_in[5];
    const float* Whh = (const float*)d_in[6];
    const float* bih = (const float*)d_in[7];
    const float* bhh = (const float*)d_in[8];
    const float* Wa = (const float*)d_in[9];
    const float* Wh = (const float*)d_in[10];
    const float* bh = (const float*)d_in[11];
    const float* Wc = (const float*)d_in[12];
    const float* bc = (const float*)d_in[13];
    const float* blog = (const float*)d_in[14];
    float* out = (float*)d_out;

    char* w = (char*)d_ws;
    auto alloc = [&](size_t bytes) { char* p = w; w += (bytes + 255) & ~(size_t)255; return p; };
    __bf16* embW_bf = (__bf16*)alloc((size_t)V_ * D_ * 2);
    __bf16* Wih_bf  = (__bf16*)alloc((size_t)G3_ * 1024 * 2);
    __bf16* Wa_bf   = (__bf16*)alloc((size_t)R_ * E_ * 2);
    __bf16* Wc_bf   = (__bf16*)alloc((size_t)D_ * E_ * 2);
    __bf16* enc_bf  = (__bf16*)alloc((size_t)BT_ * E_ * 2);
    __bf16* emb_bf  = (__bf16*)alloc((size_t)BT_ * D_ * 2);
    float* gxe      = (float*)alloc((size_t)T_ * G3_ * B_ * 4);
    float* encproj  = (float*)alloc((size_t)BT_ * R_ * 4);
    float* encWc    = (float*)alloc((size_t)BT_ * D_ * 4);
    f16* Wg         = (f16*)alloc((size_t)G3_ * 1024 * 2);
    f16* whf16      = (f16*)alloc((size_t)512 * 512 * 2);
    f16* epf16      = (f16*)alloc((size_t)BT_ * 512 * 2);
    f16* encWcT     = (f16*)alloc((size_t)32 * 512 * 64 * 2);
    f16* x16        = (f16*)alloc((size_t)2 * 32 * 1024 * 2);
    float* hbuf     = (float*)alloc((size_t)2 * 32 * 512 * 4);
    __bf16* o_bf    = (__bf16*)alloc((size_t)BT_ * D_ * 2);

    // 1) converts
    k_convert_bf16<<<(V_ * D_ / 8 + 255) / 256, 256, 0, stream>>>(embW, embW_bf, V_ * D_ / 8);
    k_convert_bf16<<<(G3_ * 1024 / 8 + 255) / 256, 256, 0, stream>>>(Wih, Wih_bf, G3_ * 1024 / 8);
    k_convert_bf16<<<(R_ * E_ / 8 + 255) / 256, 256, 0, stream>>>(Wa, Wa_bf, R_ * E_ / 8);
    k_convert_bf16<<<(D_ * E_ / 8 + 255) / 256, 256, 0, stream>>>(Wc, Wc_bf, D_ * E_ / 8);
    k_convert_bf16<<<(BT_ * E_ / 8 + 255) / 256, 256, 0, stream>>>(enc, enc_bf, BT_ * E_ / 8);

    // 2) gather embedding rows
    k_gather_emb<<<(BT_ * 64) / 256, 256, 0, stream>>>(trg, embW_bf, emb_bf);

    // 3) gx_emb = emb @ W_ih[:, :512]^T + b_ih -> [t][j][b]
    k_gemm_bf16<<<(BT_ / 128) * (G3_ / 128), 256, 0, stream>>>(
        emb_bf, Wih_bf, bih, gxe, BT_, G3_, 512, 512, 1024, 1);

    // 4) enc_proj = enc @ W_a^T; encWc = enc @ W_c^T
    k_gemm_bf16<<<(BT_ / 128) * (R_ / 128), 256, 0, stream>>>(
        enc_bf, Wa_bf, nullptr, encproj, BT_, R_, 512, 512, 512, 0);
    k_gemm_bf16<<<(BT_ / 128) * (D_ / 128), 256, 0, stream>>>(
        enc_bf, Wc_bf, nullptr, encWc, BT_, D_, 512, 512, 512, 0);

    // 5) pack weights / state
    k_pack_gates<<<(G3_ * 1024) / 256, 256, 0, stream>>>(Wih, Whh, Wg);
    k_convert_f16<<<(512 * 512 / 8 + 255) / 256, 256, 0, stream>>>(Wh, whf16, 512 * 512 / 8);
    k_convert_f16<<<(BT_ * 512 / 8 + 255) / 256, 256, 0, stream>>>(encproj, epf16, BT_ * 512 / 8);
    k_pack_ewT<<<(32 * 512 * 64) / 256, 256, 0, stream>>>(encWc, encWcT);
    k_init_state<<<(32 * 1024) / 256, 256, 0, stream>>>(init_h, x16, hbuf);

    // 6) recurrence: 2 kernels per step (graph-replayed launch gap < device barrier)
    for (int t = 0; t < T_; ++t) {
        const f16* x_in = x16 + (size_t)(t & 1) * 32 * 1024;
        f16* x_out = x16 + (size_t)((t + 1) & 1) * 32 * 1024;
        const float* h_in = hbuf + (size_t)(t & 1) * 32 * 512;
        float* h_out = hbuf + (size_t)((t + 1) & 1) * 32 * 512;
        k_stepA<<<128, 256, 0, stream>>>(Wg, gxe + (size_t)t * G3_ * B_, bhh,
                                         x_in, x_out, h_in, h_out);
        k_stepB<<<64, 256, 0, stream>>>(whf16, epf16, encWcT, mask, bh, bc,
                                        x_out, o_bf, t);
    }

    // 7) logits = o @ emb_W^T + b_logits
    k_gemm_bf16<<<(BT_ / 128) * (V_ / 128), 256, 0, stream>>>(
        o_bf, embW_bf, blog, out, BT_, V_, 512, 512, 512, 0);
}